// Round 5
// baseline (1131.777 us; speedup 1.0000x reference)
//
#include <hip/hip_runtime.h>

// ---------------------------------------------------------------------------
// AttDual round 5: fused GEMM+bias+LN+GELU blocks (64 rows x FULL 1024 cols,
// 8 waves, B streamed from L2 per K-step). No pre-LN H roundtrip, no convert
// pass (K-GEMM converts fp32 A while staging), q_max = gather of Qb rows.
// bf16 MFMA 16x16x32, fp32 accumulate, conflict-free LDS swizzle (r4-proven).
// ---------------------------------------------------------------------------

typedef unsigned short u16;
typedef __attribute__((ext_vector_type(8))) short          bf16x8;
typedef __attribute__((ext_vector_type(8))) unsigned short u16x8;
typedef __attribute__((ext_vector_type(4))) unsigned short u16x4;
typedef __attribute__((ext_vector_type(4))) float          f32x4;

#define DDIM  1024
#define NROWS 50000
#define MP    50048      // 782 * 64 padded rows
#define NBLK  782
#define NCLS  7

__device__ __forceinline__ u16 f2bf(float f) {          // RNE fp32 -> bf16
  unsigned u = __float_as_uint(f);
  u = (u + 0x7FFFu + ((u >> 16) & 1u)) >> 16;
  return (u16)u;
}
__device__ __forceinline__ float bf2f(u16 h) {
  return __uint_as_float(((unsigned)h) << 16);
}
__device__ __forceinline__ float gelu(float x) {
  return 0.5f * x * (1.0f + erff(x * 0.70710678118654752f));
}

__device__ __forceinline__ void load16_lds(const u16* g, u16* l) {
  __builtin_amdgcn_global_load_lds(
      (const __attribute__((address_space(1))) unsigned int*)(const void*)g,
      (__attribute__((address_space(3))) unsigned int*)(void*)l, 16, 0, 0);
}

// ------------------------- 3 weight matrices -> Wk, Wvq=concat(Wv,Wq) ------
__global__ __launch_bounds__(256) void k_convw(const float* __restrict__ kw,
                                               const float* __restrict__ vw,
                                               const float* __restrict__ qw,
                                               u16* __restrict__ Wk,
                                               u16* __restrict__ Wvq) {
  const int w = blockIdx.x >> 7;
  const int b = blockIdx.x & 127;
  const float* src = (w == 0) ? kw : (w == 1) ? vw : qw;
  u16* dst = (w == 0) ? Wk : (Wvq + (size_t)(w - 1) * DDIM * DDIM);
  for (int i = b * 256 + threadIdx.x; i < DDIM * DDIM / 8; i += 128 * 256) {
    const float4* p = (const float4*)(src + (size_t)i * 8);
    float4 f0 = p[0], f1 = p[1];
    u16x8 o;
    o[0] = f2bf(f0.x); o[1] = f2bf(f0.y); o[2] = f2bf(f0.z); o[3] = f2bf(f0.w);
    o[4] = f2bf(f1.x); o[5] = f2bf(f1.y); o[6] = f2bf(f1.z); o[7] = f2bf(f1.w);
    *(u16x8*)(dst + (size_t)i * 8) = o;
  }
}

// ------------------------- fused GEMM + bias + LN + GELU -------------------
// Block: 64 rows x 1024 cols. 8 waves, each 64 rows x 128 cols (acc[4][8]).
// A: 64x32 tile (fp32-converting reg path for AFP32, else global_load_lds).
// B: full 1024x32 K-slice staged per step (L2-resident weight).
// LDS swizzle: 16B slot ^= ((row>>1)&3) on both write and read (2-way, free).
template<int AFP32>
__global__ __launch_bounds__(512, 2) void k_gemm_ln(const float* __restrict__ Af,
                                                    const u16* __restrict__ Ab,
                                                    const u16* __restrict__ Bw,
                                                    const float* __restrict__ bias,
                                                    const float* __restrict__ gain,
                                                    const float* __restrict__ beta,
                                                    u16* __restrict__ Out) {
  const int tid = threadIdx.x;
  const int v = (blockIdx.x & 7) * 98 + (blockIdx.x >> 3);   // 784 = 8*98 bijective
  if (v >= NBLK) return;                                     // uniform, pre-barrier
  const int r0 = v * 64;
  const int lane = tid & 63;
  const int wid = tid >> 6;
  const int fr = lane & 15;
  const int T = lane >> 4;
  const int cb = wid * 128;
  const int sw16 = (T ^ ((fr >> 1) & 3)) << 3;   // swizzled 16B slot (elems)

  __shared__ __align__(16) u16 As[2][64 * 32];       // 8 KB
  __shared__ __align__(16) u16 Bs[2][1024 * 32];     // 128 KB
  __shared__ float red1[8][64], red2[8][64];
  __shared__ float muS[64], rsS[64];

  f32x4 acc[4][8] = {};

  // A staging geometry (threads 0..255)
  const int arow = tid >> 2;                 // 0..63 when tid<256
  const int aslotl = tid & 3;                // logical 8-elem slot
  const int asw = aslotl ^ ((arow >> 1) & 3);

#define STAGE_B(K0, BUF) do {                                                  \
    _Pragma("unroll") for (int l = 0; l < 8; ++l) {                            \
      const int c = l * 512 + tid;                                             \
      const int row_ = c >> 2;                                                 \
      const int slot_ = (c & 3) ^ ((row_ >> 1) & 3);                           \
      load16_lds(Bw + (size_t)row_ * DDIM + (K0) + slot_ * 8,                  \
                 &Bs[BUF][(size_t)c * 8]);                                     \
    } } while (0)

#define COMPUTE(BUF) do {                                                      \
    const u16* _As = &As[BUF][0];                                              \
    const u16* _Bs = &Bs[BUF][0];                                              \
    bf16x8 af[4]; bf16x8 bfr[8];                                               \
    _Pragma("unroll") for (int mi = 0; mi < 4; ++mi)                           \
      af[mi] = *(const bf16x8*)&_As[(mi * 16 + fr) * 32 + sw16];               \
    _Pragma("unroll") for (int nj = 0; nj < 8; ++nj)                           \
      bfr[nj] = *(const bf16x8*)&_Bs[(cb + nj * 16 + fr) * 32 + sw16];         \
    _Pragma("unroll") for (int mi = 0; mi < 4; ++mi)                           \
      _Pragma("unroll") for (int nj = 0; nj < 8; ++nj)                         \
        acc[mi][nj] = __builtin_amdgcn_mfma_f32_16x16x32_bf16(af[mi], bfr[nj], \
                                                              acc[mi][nj], 0, 0, 0); \
  } while (0)

  // prologue: stage kt=0 into buf 0
  STAGE_B(0, 0);
  if (tid < 256) {
    const int grow = r0 + arow;
    if (AFP32) {
      u16x8 o = {0, 0, 0, 0, 0, 0, 0, 0};
      if (grow < NROWS) {
        const float* sp = Af + (size_t)grow * DDIM + aslotl * 8;
        float4 fa = *(const float4*)sp, fb = *(const float4*)(sp + 4);
        o[0] = f2bf(fa.x); o[1] = f2bf(fa.y); o[2] = f2bf(fa.z); o[3] = f2bf(fa.w);
        o[4] = f2bf(fb.x); o[5] = f2bf(fb.y); o[6] = f2bf(fb.z); o[7] = f2bf(fb.w);
      }
      *(u16x8*)&As[0][arow * 32 + (asw << 3)] = o;
    } else {
      load16_lds(Ab + (size_t)grow * DDIM + asw * 8, &As[0][tid * 8]);
    }
  }
  __syncthreads();

  for (int kt = 0; kt < 32; ++kt) {
    const int cur = kt & 1;
    float4 fa = {0.f, 0.f, 0.f, 0.f}, fb = {0.f, 0.f, 0.f, 0.f};
    bool av = false;
    if (kt < 31) {
      const int k0 = (kt + 1) * 32;
      if (AFP32) {
        if (tid < 256) {
          const int grow = r0 + arow;
          av = grow < NROWS;
          if (av) {
            const float* sp = Af + (size_t)grow * DDIM + k0 + aslotl * 8;
            fa = *(const float4*)sp; fb = *(const float4*)(sp + 4);
          }
        }
      } else {
        if (tid < 256)
          load16_lds(Ab + (size_t)(r0 + arow) * DDIM + k0 + asw * 8,
                     &As[cur ^ 1][tid * 8]);
      }
      STAGE_B(k0, cur ^ 1);
    }
    COMPUTE(cur);
    if (AFP32) {
      if (kt < 31 && tid < 256) {
        u16x8 o = {0, 0, 0, 0, 0, 0, 0, 0};
        if (av) {
          o[0] = f2bf(fa.x); o[1] = f2bf(fa.y); o[2] = f2bf(fa.z); o[3] = f2bf(fa.w);
          o[4] = f2bf(fb.x); o[5] = f2bf(fb.y); o[6] = f2bf(fb.z); o[7] = f2bf(fb.w);
        }
        *(u16x8*)&As[cur ^ 1][arow * 32 + (asw << 3)] = o;
      }
    }
    __syncthreads();
  }
#undef STAGE_B
#undef COMPUTE

  // ---- epilogue: bias + LN (full 1024-col row in-block) + GELU, bf16 store
  float bsv[8], gsv[8], tsv[8];
#pragma unroll
  for (int nj = 0; nj < 8; ++nj) {
    const int col = cb + nj * 16 + fr;
    bsv[nj] = bias[col]; gsv[nj] = gain[col]; tsv[nj] = beta[col];
  }
  float s1a[4][4], s2a[4][4];
#pragma unroll
  for (int mi = 0; mi < 4; ++mi)
#pragma unroll
    for (int r = 0; r < 4; ++r) {
      float s1 = 0.f, s2 = 0.f;
#pragma unroll
      for (int nj = 0; nj < 8; ++nj) {
        const float h = acc[mi][nj][r] + bsv[nj];
        s1 += h; s2 += h * h;
      }
#pragma unroll
      for (int m = 1; m < 16; m <<= 1) {        // reduce over the 16-lane group
        s1 += __shfl_xor(s1, m, 64);
        s2 += __shfl_xor(s2, m, 64);
      }
      s1a[mi][r] = s1; s2a[mi][r] = s2;
    }
  if (fr == 0) {
#pragma unroll
    for (int mi = 0; mi < 4; ++mi)
#pragma unroll
      for (int r = 0; r < 4; ++r) {
        const int row = mi * 16 + T * 4 + r;
        red1[wid][row] = s1a[mi][r];
        red2[wid][row] = s2a[mi][r];
      }
  }
  __syncthreads();
  if (tid < 64) {
    float S1 = 0.f, S2 = 0.f;
#pragma unroll
    for (int w = 0; w < 8; ++w) { S1 += red1[w][tid]; S2 += red2[w][tid]; }
    const float mu = S1 * (1.0f / 1024.0f);
    const float var = S2 * (1.0f / 1024.0f) - mu * mu;
    muS[tid] = mu;
    rsS[tid] = rsqrtf(var + 1e-5f);
  }
  __syncthreads();
#pragma unroll
  for (int mi = 0; mi < 4; ++mi)
#pragma unroll
    for (int r = 0; r < 4; ++r) {
      const int row = mi * 16 + T * 4 + r;
      const int grow = r0 + row;
      const float mu = muS[row], rs = rsS[row];
      const bool valid = grow < NROWS;
#pragma unroll
      for (int nj = 0; nj < 8; ++nj) {
        const float h = acc[mi][nj][r] + bsv[nj];
        const float y = gelu((h - mu) * rs * gsv[nj] + tsv[nj]);
        Out[(size_t)grow * DDIM + cb + nj * 16 + fr] = valid ? f2bf(y) : (u16)0;
      }
    }
}

// ------------------------- logits[n,j] = <Q[n], Q[top[j]]> / 32 ------------
__global__ __launch_bounds__(256) void k_logits(const u16* __restrict__ Q,
                                                const int* __restrict__ top,
                                                float* __restrict__ logits) {
  __shared__ __align__(16) u16 qm[NCLS * DDIM];
  const int tid = threadIdx.x;
  for (int i = tid; i < NCLS * (DDIM / 8); i += 256) {
    const int j = i >> 7;
    const int ch = i & 127;
    *(u16x8*)&qm[j * DDIM + ch * 8] = *(const u16x8*)&Q[(size_t)top[j] * DDIM + ch * 8];
  }
  __syncthreads();
  const int lane = tid & 63;
  const int n = blockIdx.x * 4 + (tid >> 6);
  if (n >= NROWS) return;
  const u16x8* qp = (const u16x8*)(Q + (size_t)n * DDIM + lane * 16);
  u16x8 q0 = qp[0], q1 = qp[1];
  float qf[16];
#pragma unroll
  for (int e = 0; e < 8; ++e) { qf[e] = bf2f(q0[e]); qf[e + 8] = bf2f(q1[e]); }
#pragma unroll
  for (int j = 0; j < NCLS; ++j) {
    const u16x8* mp = (const u16x8*)&qm[j * DDIM + lane * 16];
    u16x8 m0 = mp[0], m1 = mp[1];
    float p = 0.f;
#pragma unroll
    for (int e = 0; e < 8; ++e) p += qf[e] * bf2f(m0[e]) + qf[e + 8] * bf2f(m1[e]);
#pragma unroll
    for (int m = 1; m < 64; m <<= 1) p += __shfl_xor(p, m, 64);
    if (lane == 0) logits[(size_t)n * NCLS + j] = p * 0.03125f;
  }
}

// ------------------------- argmax partials (first-index) -------------------
__global__ __launch_bounds__(256) void k_arg1(const float* __restrict__ c,
                                              float* __restrict__ pv,
                                              int* __restrict__ pi) {
  __shared__ float sv[256 * NCLS];
  __shared__ int   si[256 * NCLS];
  const int t = threadIdx.x;
  float bv[NCLS]; int bi[NCLS];
#pragma unroll
  for (int j = 0; j < NCLS; ++j) { bv[j] = -3.4e38f; bi[j] = 0x7fffffff; }
  for (int n = blockIdx.x * 256 + t; n < NROWS; n += 128 * 256) {
#pragma unroll
    for (int j = 0; j < NCLS; ++j) {
      const float v = c[(size_t)n * NCLS + j];
      if (v > bv[j]) { bv[j] = v; bi[j] = n; }
    }
  }
#pragma unroll
  for (int j = 0; j < NCLS; ++j) { sv[t * NCLS + j] = bv[j]; si[t * NCLS + j] = bi[j]; }
  __syncthreads();
  for (int s = 128; s > 0; s >>= 1) {
    if (t < s) {
#pragma unroll
      for (int j = 0; j < NCLS; ++j) {
        const float v2 = sv[(t + s) * NCLS + j]; const int i2 = si[(t + s) * NCLS + j];
        const float v1 = sv[t * NCLS + j];       const int i1 = si[t * NCLS + j];
        if (v2 > v1 || (v2 == v1 && i2 < i1)) { sv[t * NCLS + j] = v2; si[t * NCLS + j] = i2; }
      }
    }
    __syncthreads();
  }
  if (t < NCLS) { pv[blockIdx.x * NCLS + t] = sv[t]; pi[blockIdx.x * NCLS + t] = si[t]; }
}

__global__ void k_arg2(const float* __restrict__ pv, const int* __restrict__ pi,
                       int* __restrict__ top) {
  __shared__ float sv[128 * NCLS];
  __shared__ int   si[128 * NCLS];
  const int t = threadIdx.x;                           // blockDim = 128
#pragma unroll
  for (int j = 0; j < NCLS; ++j) { sv[t * NCLS + j] = pv[t * NCLS + j]; si[t * NCLS + j] = pi[t * NCLS + j]; }
  __syncthreads();
  for (int s = 64; s > 0; s >>= 1) {
    if (t < s) {
#pragma unroll
      for (int j = 0; j < NCLS; ++j) {
        const float v2 = sv[(t + s) * NCLS + j]; const int i2 = si[(t + s) * NCLS + j];
        const float v1 = sv[t * NCLS + j];       const int i1 = si[t * NCLS + j];
        if (v2 > v1 || (v2 == v1 && i2 < i1)) { sv[t * NCLS + j] = v2; si[t * NCLS + j] = i2; }
      }
    }
    __syncthreads();
  }
  if (t < NCLS) top[t] = si[t];
}

// ------------------------- softmax over axis 0 -----------------------------
__global__ __launch_bounds__(256) void k_cmax_part(const float* __restrict__ logits,
                                                   float* __restrict__ pout) {
  __shared__ float sm[256 * NCLS];
  const int tid = threadIdx.x;
  float m[NCLS];
#pragma unroll
  for (int j = 0; j < NCLS; ++j) m[j] = -3.4e38f;
  const size_t stride = (size_t)gridDim.x * 256;
  for (size_t n = (size_t)blockIdx.x * 256 + tid; n < NROWS; n += stride)
#pragma unroll
    for (int j = 0; j < NCLS; ++j) m[j] = fmaxf(m[j], logits[n * NCLS + j]);
#pragma unroll
  for (int j = 0; j < NCLS; ++j) sm[tid * NCLS + j] = m[j];
  __syncthreads();
  for (int s = 128; s > 0; s >>= 1) {
    if (tid < s)
#pragma unroll
      for (int j = 0; j < NCLS; ++j)
        sm[tid * NCLS + j] = fmaxf(sm[tid * NCLS + j], sm[(tid + s) * NCLS + j]);
    __syncthreads();
  }
  if (tid < NCLS) pout[blockIdx.x * NCLS + tid] = sm[tid];
}

// csum_part also does the max-fin per block (deterministic serial order).
__global__ __launch_bounds__(256) void k_csum_part(const float* __restrict__ logits,
                                                   const float* __restrict__ Pmax,
                                                   float* __restrict__ pout) {
  __shared__ float sm[256 * NCLS];
  __shared__ float sM[NCLS];
  const int tid = threadIdx.x;
  if (tid < NCLS) {
    float m = -3.4e38f;
    for (int b = 0; b < 128; ++b) m = fmaxf(m, Pmax[b * NCLS + tid]);
    sM[tid] = m;
  }
  __syncthreads();
  float s[NCLS];
#pragma unroll
  for (int j = 0; j < NCLS; ++j) s[j] = 0.f;
  const size_t stride = (size_t)gridDim.x * 256;
  for (size_t n = (size_t)blockIdx.x * 256 + tid; n < NROWS; n += stride)
#pragma unroll
    for (int j = 0; j < NCLS; ++j) s[j] += expf(logits[n * NCLS + j] - sM[j]);
#pragma unroll
  for (int j = 0; j < NCLS; ++j) sm[tid * NCLS + j] = s[j];
  __syncthreads();
  for (int st = 128; st > 0; st >>= 1) {
    if (tid < st)
#pragma unroll
      for (int j = 0; j < NCLS; ++j) sm[tid * NCLS + j] += sm[(tid + st) * NCLS + j];
    __syncthreads();
  }
  if (tid < NCLS) pout[blockIdx.x * NCLS + tid] = sm[tid];
}

// ------------------------- B-partials = A^T V, fused A-write + fins --------
__global__ __launch_bounds__(256) void k_bpart(const float* __restrict__ logits,
                                               const float* __restrict__ Pmax,
                                               const float* __restrict__ Psum,
                                               const u16* __restrict__ V,
                                               float* __restrict__ Aout,
                                               float* __restrict__ Pb) {
  __shared__ float sA[98 * NCLS];
  __shared__ float sM[NCLS], sR[NCLS];
  const int t = threadIdx.x;
  if (t < NCLS) {
    float m = -3.4e38f;
    for (int b = 0; b < 128; ++b) m = fmaxf(m, Pmax[b * NCLS + t]);   // same order
    float s = 0.f;
    for (int b = 0; b < 128; ++b) s += Psum[b * NCLS + t];
    sM[t] = m; sR[t] = 1.0f / s;
  }
  __syncthreads();
  const int n0 = blockIdx.x * 98;
  int cnt = NROWS - n0;
  cnt = cnt < 0 ? 0 : (cnt > 98 ? 98 : cnt);
  for (int idx = t; idx < cnt * NCLS; idx += 256) {
    const int j = idx % NCLS;
    const float a = expf(logits[(size_t)n0 * NCLS + idx] - sM[j]) * sR[j];
    sA[idx] = a;
    Aout[(size_t)n0 * NCLS + idx] = a;
  }
  __syncthreads();
  float acc[NCLS][4] = {};
  for (int r = 0; r < cnt; ++r) {
    u16x4 vv = *(const u16x4*)&V[(size_t)(n0 + r) * DDIM + t * 4];
    const float f0 = bf2f(vv[0]), f1 = bf2f(vv[1]), f2 = bf2f(vv[2]), f3 = bf2f(vv[3]);
#pragma unroll
    for (int j = 0; j < NCLS; ++j) {
      const float a = sA[r * NCLS + j];
      acc[j][0] += a * f0; acc[j][1] += a * f1; acc[j][2] += a * f2; acc[j][3] += a * f3;
    }
  }
#pragma unroll
  for (int j = 0; j < NCLS; ++j) {
    f32x4 o = {acc[j][0], acc[j][1], acc[j][2], acc[j][3]};
    *(f32x4*)&Pb[((size_t)blockIdx.x * NCLS + j) * DDIM + t * 4] = o;
  }
}

__global__ void k_bred(const float* __restrict__ Pb, float* __restrict__ Bout) {
  const int idx = blockIdx.x * 256 + threadIdx.x;
  if (idx >= NCLS * DDIM) return;
  float s = 0.f;
  for (int p = 0; p < 512; ++p) s += Pb[(size_t)p * NCLS * DDIM + idx];
  Bout[idx] = s;
}

// ------------------------- C[o] = <B, head_w[o]> + head_b[o] ---------------
__global__ __launch_bounds__(256) void k_head(const float* __restrict__ Bmat,
                                              const float* __restrict__ hw,
                                              const float* __restrict__ hb,
                                              float* __restrict__ Cout) {
  const int o = blockIdx.x, t = threadIdx.x;
  float p = 0.f;
  for (int idx = t; idx < NCLS * DDIM; idx += 256)
    p += Bmat[idx] * hw[(size_t)o * NCLS * DDIM + idx];
#pragma unroll
  for (int m = 1; m < 64; m <<= 1) p += __shfl_xor(p, m, 64);
  __shared__ float w[4];
  if ((t & 63) == 0) w[t >> 6] = p;
  __syncthreads();
  if (t == 0) Cout[o] = w[0] + w[1] + w[2] + w[3] + hb[o];
}

// ---------------------------------------------------------------------------
extern "C" void kernel_launch(void* const* d_in, const int* in_sizes, int n_in,
                              void* d_out, int out_size, void* d_ws, size_t ws_size,
                              hipStream_t stream) {
  const float* features   = (const float*)d_in[0];
  const float* c_in       = (const float*)d_in[1];
  const float* key_w      = (const float*)d_in[2];
  const float* key_b      = (const float*)d_in[3];
  const float* key_g      = (const float*)d_in[4];
  const float* key_beta   = (const float*)d_in[5];
  const float* query_w    = (const float*)d_in[6];
  const float* query_b    = (const float*)d_in[7];
  const float* query_g    = (const float*)d_in[8];
  const float* query_beta = (const float*)d_in[9];
  const float* value_w    = (const float*)d_in[10];
  const float* value_b    = (const float*)d_in[11];
  const float* value_g    = (const float*)d_in[12];
  const float* value_beta = (const float*)d_in[13];
  const float* head_w     = (const float*)d_in[14];
  const float* head_b     = (const float*)d_in[15];

  char* ws = (char*)d_ws;
  const size_t SZB = (size_t)MP * DDIM * 2;             // 102,498,304 B
  u16* Kb = (u16*)ws;
  u16* Vb = (u16*)(ws + SZB);
  u16* Qb = (u16*)(ws + 2 * SZB);
  size_t off = 3 * SZB;
  u16* Wk  = (u16*)(ws + off); off += (size_t)DDIM * DDIM * 2;
  u16* Wvq = (u16*)(ws + off); off += (size_t)2 * DDIM * DDIM * 2;
  float* logits = (float*)(ws + off); off += ((size_t)NROWS * NCLS * 4 + 255) & ~(size_t)255;
  float* Pb  = (float*)(ws + off); off += (size_t)512 * NCLS * DDIM * 4;
  float* Pmax = (float*)(ws + off); off += ((size_t)128 * NCLS * 4 + 255) & ~(size_t)255;
  float* Psum = (float*)(ws + off); off += ((size_t)128 * NCLS * 4 + 255) & ~(size_t)255;
  float* argv = (float*)(ws + off); off += ((size_t)128 * NCLS * 4 + 255) & ~(size_t)255;
  int*   argi = (int*)  (ws + off); off += ((size_t)128 * NCLS * 4 + 255) & ~(size_t)255;
  int*   top  = (int*)  (ws + off); off += 256;

  float* Cout = (float*)d_out;                          // [7]
  float* Aout = Cout + NCLS;                            // [50000,7]
  float* Bout = Aout + (size_t)NROWS * NCLS;            // [7,1024]

  // argmax (independent) + weight converts
  k_arg1<<<128, 256, 0, stream>>>(c_in, argv, argi);
  k_arg2<<<1, 128, 0, stream>>>(argv, argi, top);
  k_convw<<<384, 256, 0, stream>>>(key_w, value_w, query_w, Wk, Wvq);

  // fused chains: K = LN(X Wk^T + b) etc., no pre-LN H roundtrip
  k_gemm_ln<1><<<784, 512, 0, stream>>>(features, nullptr, Wk,
                                        key_b, key_g, key_beta, Kb);
  k_gemm_ln<0><<<784, 512, 0, stream>>>(nullptr, Kb, Wvq,
                                        value_b, value_g, value_beta, Vb);
  k_gemm_ln<0><<<784, 512, 0, stream>>>(nullptr, Kb, Wvq + (size_t)DDIM * DDIM,
                                        query_b, query_g, query_beta, Qb);

  // logits vs q_max = Qb[top] (gathered in-kernel), softmax over axis 0
  k_logits<<<(NROWS + 3) / 4, 256, 0, stream>>>(Qb, top, logits);
  k_cmax_part<<<128, 256, 0, stream>>>(logits, Pmax);
  k_csum_part<<<128, 256, 0, stream>>>(logits, Pmax, Psum);

  // B = A^T V (A materialized on the fly), head contraction
  k_bpart<<<512, 256, 0, stream>>>(logits, Pmax, Psum, Vb, Aout, Pb);
  k_bred<<<28, 256, 0, stream>>>(Pb, Bout);
  k_head<<<NCLS, 256, 0, stream>>>(Bout, head_w, head_b, Cout);
}

// Round 6
// 746.183 us; speedup vs baseline: 1.5168x; 1.5168x over previous
//
#include <hip/hip_runtime.h>

// ---------------------------------------------------------------------------
// AttDual round 6: r2's proven single-buffer 128^2 GEMM (+r4 conflict swizzle)
// with fp32-A reg-staged K-GEMM (no convert pass), r3 small-kernel fusions,
// one-pass softmax partials with rescale-fin. bf16 MFMA, fp32 accumulate.
// ---------------------------------------------------------------------------

typedef unsigned short u16;
typedef __attribute__((ext_vector_type(8))) short          bf16x8;
typedef __attribute__((ext_vector_type(8))) unsigned short u16x8;
typedef __attribute__((ext_vector_type(4))) unsigned short u16x4;
typedef __attribute__((ext_vector_type(4))) float          f32x4;

#define DDIM  1024
#define NROWS 50000
#define MP    50048      // 391 * 128 padded rows (zeros)
#define NCLS  7
#define MPD4  12512      // MP/4

__device__ __forceinline__ u16 f2bf(float f) {          // RNE fp32 -> bf16
  unsigned u = __float_as_uint(f);
  u = (u + 0x7FFFu + ((u >> 16) & 1u)) >> 16;
  return (u16)u;
}
__device__ __forceinline__ float bf2f(u16 h) {
  return __uint_as_float(((unsigned)h) << 16);
}
__device__ __forceinline__ float gelu(float x) {
  return 0.5f * x * (1.0f + erff(x * 0.70710678118654752f));
}

__device__ __forceinline__ void load16_lds(const u16* g, u16* l) {
  __builtin_amdgcn_global_load_lds(
      (const __attribute__((address_space(1))) unsigned int*)(const void*)g,
      (__attribute__((address_space(3))) unsigned int*)(void*)l, 16, 0, 0);
}

// ------------------------- 3 weight matrices -> Wk, Wvq=concat(Wv,Wq) ------
__global__ __launch_bounds__(256) void k_convw(const float* __restrict__ kw,
                                               const float* __restrict__ vw,
                                               const float* __restrict__ qw,
                                               u16* __restrict__ Wk,
                                               u16* __restrict__ Wvq) {
  const int w = blockIdx.x >> 7;
  const int b = blockIdx.x & 127;
  const float* src = (w == 0) ? kw : (w == 1) ? vw : qw;
  u16* dst = (w == 0) ? Wk : (Wvq + (size_t)(w - 1) * DDIM * DDIM);
  for (int i = b * 256 + threadIdx.x; i < DDIM * DDIM / 8; i += 128 * 256) {
    const float4* p = (const float4*)(src + (size_t)i * 8);
    float4 f0 = p[0], f1 = p[1];
    u16x8 o;
    o[0] = f2bf(f0.x); o[1] = f2bf(f0.y); o[2] = f2bf(f0.z); o[3] = f2bf(f0.w);
    o[4] = f2bf(f1.x); o[5] = f2bf(f1.y); o[6] = f2bf(f1.z); o[7] = f2bf(f1.w);
    *(u16x8*)(dst + (size_t)i * 8) = o;
  }
}

// ------------------------- bf16 GEMM core (r2 structure + r4 swizzle) ------
// C[m,n] = sum_k A[m,k]*B[n,k]. 128x128 tile, BK=32, 4 waves, single-buffer
// 2-barrier loop. LDS linear for global_load_lds; GLOBAL source slot is
// XOR-swizzled by ((row>>1)&3); reads apply same involution (2 lanes/bank).
// AFP32: A read as fp32 with reg-staged convert + zero row padding.
template<int AFP32>
__global__ __launch_bounds__(256) void k_gemm(const float* __restrict__ Af,
                                              const u16* __restrict__ Ab,
                                              const u16* __restrict__ B,
                                              u16* __restrict__ C,
                                              int lnn, int ldc) {
  __shared__ __align__(16) u16 As[128 * 32];
  __shared__ __align__(16) u16 Bs[128 * 32];
  const int tid  = threadIdx.x;
  const int lane = tid & 63;
  const int cpx = gridDim.x >> 3;                       // nwg % 8 == 0
  const int v   = (blockIdx.x & 7) * cpx + (blockIdx.x >> 3);
  const int m0 = (v >> lnn) * 128;
  const int n0 = (v & ((1 << lnn) - 1)) * 128;
  const int wid = tid >> 6;
  const int wr = (wid >> 1) * 64;
  const int wc = (wid & 1) * 64;

  const int rA = tid >> 2;                              // 0..63
  const int slotl = tid & 3;                            // logical 8-elem slot
  const int swz = (rA >> 1) & 3;                        // same for rA and rA+64
  const int cA = ((slotl ^ swz) << 3);                  // swizzled source slot
  const u16* Bp0 = B + (size_t)(n0 + rA) * DDIM + cA;
  const u16* Bp1 = Bp0 + (size_t)64 * DDIM;
  const u16* Ap0 = nullptr; const u16* Ap1 = nullptr;
  const float* Fp0 = nullptr; const float* Fp1 = nullptr;
  bool av0 = false, av1 = false;
  if (AFP32) {
    av0 = (m0 + rA) < NROWS;
    av1 = (m0 + rA + 64) < NROWS;
    Fp0 = Af + (size_t)(m0 + rA) * DDIM + slotl * 8;      // logical slot
    Fp1 = Fp0 + (size_t)64 * DDIM;
  } else {
    Ap0 = Ab + (size_t)(m0 + rA) * DDIM + cA;
    Ap1 = Ap0 + (size_t)64 * DDIM;
  }
  const int wbase = wid * 64;                           // wave-uniform chunk
  u16* AsD0 = &As[(wbase)       * 8];
  u16* AsD1 = &As[(wbase + 256) * 8];
  u16* BsD0 = &Bs[(wbase)       * 8];
  u16* BsD1 = &Bs[(wbase + 256) * 8];
  // reg-staged A writes to the swizzled slot directly
  u16* AsW0 = &As[rA * 32 + (cA ^ 0)];                  // cA already swizzled
  u16* AsW1 = &As[(rA + 64) * 32 + cA];

  f32x4 acc[4][4] = {};
  const int fr = lane & 15;
  const int T  = lane >> 4;

  for (int k0 = 0; k0 < DDIM; k0 += 32) {
    float4 fa0, fb0, fa1, fb1;
    if (AFP32) {          // issue global fp32 loads early (overlap prev MFMA)
      if (av0) { fa0 = *(const float4*)(Fp0 + k0); fb0 = *(const float4*)(Fp0 + k0 + 4); }
      if (av1) { fa1 = *(const float4*)(Fp1 + k0); fb1 = *(const float4*)(Fp1 + k0 + 4); }
    }
    __syncthreads();                     // previous iter's reads done
    if (AFP32) {
      u16x8 o0 = {0,0,0,0,0,0,0,0}, o1 = {0,0,0,0,0,0,0,0};
      if (av0) {
        o0[0]=f2bf(fa0.x); o0[1]=f2bf(fa0.y); o0[2]=f2bf(fa0.z); o0[3]=f2bf(fa0.w);
        o0[4]=f2bf(fb0.x); o0[5]=f2bf(fb0.y); o0[6]=f2bf(fb0.z); o0[7]=f2bf(fb0.w);
      }
      if (av1) {
        o1[0]=f2bf(fa1.x); o1[1]=f2bf(fa1.y); o1[2]=f2bf(fa1.z); o1[3]=f2bf(fa1.w);
        o1[4]=f2bf(fb1.x); o1[5]=f2bf(fb1.y); o1[6]=f2bf(fb1.z); o1[7]=f2bf(fb1.w);
      }
      *(u16x8*)AsW0 = o0;
      *(u16x8*)AsW1 = o1;
    } else {
      load16_lds(Ap0 + k0, AsD0);
      load16_lds(Ap1 + k0, AsD1);
    }
    load16_lds(Bp0 + k0, BsD0);
    load16_lds(Bp1 + k0, BsD1);
    __syncthreads();                     // full drain (compiler-inserted)
    bf16x8 a[4], b[4];
#pragma unroll
    for (int i = 0; i < 4; ++i) {
      const int R = wr + i * 16 + fr;
      a[i] = *(const bf16x8*)&As[R * 32 + ((T ^ ((R >> 1) & 3)) << 3)];
    }
#pragma unroll
    for (int j = 0; j < 4; ++j) {
      const int R = wc + j * 16 + fr;
      b[j] = *(const bf16x8*)&Bs[R * 32 + ((T ^ ((R >> 1) & 3)) << 3)];
    }
#pragma unroll
    for (int i = 0; i < 4; ++i)
#pragma unroll
      for (int j = 0; j < 4; ++j)
        acc[i][j] = __builtin_amdgcn_mfma_f32_16x16x32_bf16(a[i], b[j], acc[i][j], 0, 0, 0);
  }

  const int orow = (lane >> 4) * 4;
  const int ocol = lane & 15;
#pragma unroll
  for (int i = 0; i < 4; ++i)
#pragma unroll
    for (int j = 0; j < 4; ++j) {
      const size_t base = (size_t)(m0 + wr + i * 16 + orow) * ldc + (n0 + wc + j * 16 + ocol);
#pragma unroll
      for (int r = 0; r < 4; ++r)
        C[base + (size_t)r * ldc] = f2bf(acc[i][j][r]);
    }
}

// ------------------------- bias + LN + GELU for K (zero-pads rows) ---------
__global__ __launch_bounds__(256) void k_ln_k(const u16* __restrict__ h,
                                              const float* __restrict__ bias,
                                              const float* __restrict__ g,
                                              const float* __restrict__ beta,
                                              u16* __restrict__ out) {
  const int lane = threadIdx.x & 63;
  const int row = blockIdx.x * 4 + (threadIdx.x >> 6);
  const int c0 = lane * 8;
  u16x8* op0 = (u16x8*)(out + (size_t)row * DDIM + c0);
  u16x8* op1 = (u16x8*)(out + (size_t)row * DDIM + 512 + c0);
  if (row >= NROWS) {
    u16x8 z = {0, 0, 0, 0, 0, 0, 0, 0};
    *op0 = z; *op1 = z;
    return;
  }
  u16x8 h0 = *(const u16x8*)(h + (size_t)row * DDIM + c0);
  u16x8 h1 = *(const u16x8*)(h + (size_t)row * DDIM + 512 + c0);
  float4 a0 = *(const float4*)(bias + c0), a1 = *(const float4*)(bias + c0 + 4);
  float4 a2 = *(const float4*)(bias + 512 + c0), a3 = *(const float4*)(bias + 512 + c0 + 4);
  const float ba[8] = {a0.x, a0.y, a0.z, a0.w, a1.x, a1.y, a1.z, a1.w};
  const float bb[8] = {a2.x, a2.y, a2.z, a2.w, a3.x, a3.y, a3.z, a3.w};
  float v0[8], v1[8];
  float s1 = 0.f, s2 = 0.f;
#pragma unroll
  for (int e = 0; e < 8; ++e) {
    v0[e] = bf2f(h0[e]) + ba[e];
    v1[e] = bf2f(h1[e]) + bb[e];
    s1 += v0[e] + v1[e];
    s2 += v0[e] * v0[e] + v1[e] * v1[e];
  }
#pragma unroll
  for (int m = 1; m < 64; m <<= 1) {
    s1 += __shfl_xor(s1, m, 64);
    s2 += __shfl_xor(s2, m, 64);
  }
  const float mu = s1 * (1.0f / 1024.0f);
  const float var = s2 * (1.0f / 1024.0f) - mu * mu;
  const float rs = rsqrtf(var + 1e-5f);
  float4 g0 = *(const float4*)(g + c0), g1 = *(const float4*)(g + c0 + 4);
  float4 g2 = *(const float4*)(g + 512 + c0), g3 = *(const float4*)(g + 512 + c0 + 4);
  float4 t0 = *(const float4*)(beta + c0), t1 = *(const float4*)(beta + c0 + 4);
  float4 t2 = *(const float4*)(beta + 512 + c0), t3 = *(const float4*)(beta + 512 + c0 + 4);
  const float ga[8] = {g0.x, g0.y, g0.z, g0.w, g1.x, g1.y, g1.z, g1.w};
  const float gb[8] = {g2.x, g2.y, g2.z, g2.w, g3.x, g3.y, g3.z, g3.w};
  const float ta[8] = {t0.x, t0.y, t0.z, t0.w, t1.x, t1.y, t1.z, t1.w};
  const float tb[8] = {t2.x, t2.y, t2.z, t2.w, t3.x, t3.y, t3.z, t3.w};
  u16x8 o0, o1;
#pragma unroll
  for (int e = 0; e < 8; ++e) {
    o0[e] = f2bf(gelu((v0[e] - mu) * rs * ga[e] + ta[e]));
    o1[e] = f2bf(gelu((v1[e] - mu) * rs * gb[e] + tb[e]));
  }
  *op0 = o0; *op1 = o1;
}

// ------------------------- q_max from HbVQ rows (fin of argmax inside) -----
__global__ __launch_bounds__(64) void k_qmax2(const float* __restrict__ argv,
                                              const int* __restrict__ argi,
                                              const u16* __restrict__ hvq,
                                              const float* __restrict__ qb,
                                              const float* __restrict__ qg,
                                              const float* __restrict__ qbeta,
                                              u16* __restrict__ qm) {
  const int j = blockIdx.x;
  const int lane = threadIdx.x;
  float bv = -3.4e38f; int bi = 0x7fffffff;
  for (int p = lane; p < 128; p += 64) {
    const float v = argv[p * NCLS + j];
    const int   i = argi[p * NCLS + j];
    if (v > bv || (v == bv && i < bi)) { bv = v; bi = i; }
  }
#pragma unroll
  for (int m = 1; m < 64; m <<= 1) {
    const float ov = __shfl_xor(bv, m, 64);
    const int   oi = __shfl_xor(bi, m, 64);
    if (ov > bv || (ov == bv && oi < bi)) { bv = ov; bi = oi; }
  }
  const int row = bi;
  const int c0 = lane * 8;
  const u16* hp = hvq + (size_t)row * 2048 + DDIM;      // Q-half
  u16x8 h0 = *(const u16x8*)(hp + c0);
  u16x8 h1 = *(const u16x8*)(hp + 512 + c0);
  float v0[8], v1[8];
  float s1 = 0.f, s2 = 0.f;
#pragma unroll
  for (int e = 0; e < 8; ++e) {
    v0[e] = bf2f(h0[e]) + qb[c0 + e];
    v1[e] = bf2f(h1[e]) + qb[512 + c0 + e];
    s1 += v0[e] + v1[e];
    s2 += v0[e] * v0[e] + v1[e] * v1[e];
  }
#pragma unroll
  for (int m = 1; m < 64; m <<= 1) {
    s1 += __shfl_xor(s1, m, 64);
    s2 += __shfl_xor(s2, m, 64);
  }
  const float mu = s1 * (1.0f / 1024.0f);
  const float var = s2 * (1.0f / 1024.0f) - mu * mu;
  const float rs = rsqrtf(var + 1e-5f);
  u16x8 o0, o1;
#pragma unroll
  for (int e = 0; e < 8; ++e) {
    o0[e] = f2bf(gelu((v0[e] - mu) * rs * qg[c0 + e] + qbeta[c0 + e]));
    o1[e] = f2bf(gelu((v1[e] - mu) * rs * qg[512 + c0 + e] + qbeta[512 + c0 + e]));
  }
  *(u16x8*)(qm + (size_t)j * DDIM + c0) = o0;
  *(u16x8*)(qm + (size_t)j * DDIM + 512 + c0) = o1;
}

// ------------------------- merged V/Q LN; Q-half emits logits only ---------
__global__ __launch_bounds__(256) void k_ln_vq(const u16* __restrict__ h,
                                               const float* __restrict__ v_b,
                                               const float* __restrict__ v_g,
                                               const float* __restrict__ v_beta,
                                               const float* __restrict__ q_b,
                                               const float* __restrict__ q_g,
                                               const float* __restrict__ q_beta,
                                               const u16* __restrict__ qm,
                                               u16* __restrict__ V,
                                               float* __restrict__ logits) {
  __shared__ __align__(16) u16 sqm[NCLS * DDIM];        // 14 KB
  const int tid = threadIdx.x;
  const int lane = tid & 63;
  const int half = (blockIdx.x >= MPD4) ? 1 : 0;
  const int rb = half ? (blockIdx.x - MPD4) : blockIdx.x;
  const int row = rb * 4 + (tid >> 6);
  if (half) {
    for (int i = tid; i < NCLS * DDIM / 8; i += 256)
      *(u16x8*)&sqm[i * 8] = *(const u16x8*)&qm[i * 8];
    __syncthreads();
  }
  if (row >= NROWS) return;                             // no sync after this
  const float* bias = half ? q_b : v_b;
  const float* gain = half ? q_g : v_g;
  const float* bet  = half ? q_beta : v_beta;
  const int c0 = lane * 8;
  const u16* hp = h + (size_t)row * 2048 + (size_t)half * DDIM;
  u16x8 h0 = *(const u16x8*)(hp + c0);
  u16x8 h1 = *(const u16x8*)(hp + 512 + c0);
  float4 a0 = *(const float4*)(bias + c0), a1 = *(const float4*)(bias + c0 + 4);
  float4 a2 = *(const float4*)(bias + 512 + c0), a3 = *(const float4*)(bias + 512 + c0 + 4);
  const float ba[8] = {a0.x, a0.y, a0.z, a0.w, a1.x, a1.y, a1.z, a1.w};
  const float bb[8] = {a2.x, a2.y, a2.z, a2.w, a3.x, a3.y, a3.z, a3.w};
  float v0[8], v1[8];
  float s1 = 0.f, s2 = 0.f;
#pragma unroll
  for (int e = 0; e < 8; ++e) {
    v0[e] = bf2f(h0[e]) + ba[e];
    v1[e] = bf2f(h1[e]) + bb[e];
    s1 += v0[e] + v1[e];
    s2 += v0[e] * v0[e] + v1[e] * v1[e];
  }
#pragma unroll
  for (int m = 1; m < 64; m <<= 1) {
    s1 += __shfl_xor(s1, m, 64);
    s2 += __shfl_xor(s2, m, 64);
  }
  const float mu = s1 * (1.0f / 1024.0f);
  const float var = s2 * (1.0f / 1024.0f) - mu * mu;
  const float rs = rsqrtf(var + 1e-5f);
  float4 g0 = *(const float4*)(gain + c0), g1 = *(const float4*)(gain + c0 + 4);
  float4 g2 = *(const float4*)(gain + 512 + c0), g3 = *(const float4*)(gain + 512 + c0 + 4);
  float4 t0 = *(const float4*)(bet + c0), t1 = *(const float4*)(bet + c0 + 4);
  float4 t2 = *(const float4*)(bet + 512 + c0), t3 = *(const float4*)(bet + 512 + c0 + 4);
  const float ga[8] = {g0.x, g0.y, g0.z, g0.w, g1.x, g1.y, g1.z, g1.w};
  const float gb[8] = {g2.x, g2.y, g2.z, g2.w, g3.x, g3.y, g3.z, g3.w};
  const float ta[8] = {t0.x, t0.y, t0.z, t0.w, t1.x, t1.y, t1.z, t1.w};
  const float tb[8] = {t2.x, t2.y, t2.z, t2.w, t3.x, t3.y, t3.z, t3.w};
  float y0[8], y1[8];
#pragma unroll
  for (int e = 0; e < 8; ++e) {
    y0[e] = gelu((v0[e] - mu) * rs * ga[e] + ta[e]);
    y1[e] = gelu((v1[e] - mu) * rs * gb[e] + tb[e]);
  }
  if (half == 0) {
    u16x8 o0, o1;
#pragma unroll
    for (int e = 0; e < 8; ++e) { o0[e] = f2bf(y0[e]); o1[e] = f2bf(y1[e]); }
    *(u16x8*)(V + (size_t)row * DDIM + c0) = o0;
    *(u16x8*)(V + (size_t)row * DDIM + 512 + c0) = o1;
  } else {
#pragma unroll
    for (int j = 0; j < NCLS; ++j) {
      u16x8 m0 = *(const u16x8*)&sqm[j * DDIM + c0];
      u16x8 m1 = *(const u16x8*)&sqm[j * DDIM + 512 + c0];
      float p = 0.f;
#pragma unroll
      for (int e = 0; e < 8; ++e) p += y0[e] * bf2f(m0[e]) + y1[e] * bf2f(m1[e]);
#pragma unroll
      for (int m = 1; m < 64; m <<= 1) p += __shfl_xor(p, m, 64);
      if (lane == 0) logits[(size_t)row * NCLS + j] = p * 0.03125f;
    }
  }
}

// ------------------------- argmax partials (first-index) -------------------
__global__ __launch_bounds__(256) void k_arg1(const float* __restrict__ c,
                                              float* __restrict__ pv,
                                              int* __restrict__ pi) {
  __shared__ float sv[256 * NCLS];
  __shared__ int   si[256 * NCLS];
  const int t = threadIdx.x;
  float bv[NCLS]; int bi[NCLS];
#pragma unroll
  for (int j = 0; j < NCLS; ++j) { bv[j] = -3.4e38f; bi[j] = 0x7fffffff; }
  for (int n = blockIdx.x * 256 + t; n < NROWS; n += 128 * 256) {
#pragma unroll
    for (int j = 0; j < NCLS; ++j) {
      const float v = c[(size_t)n * NCLS + j];
      if (v > bv[j]) { bv[j] = v; bi[j] = n; }
    }
  }
#pragma unroll
  for (int j = 0; j < NCLS; ++j) { sv[t * NCLS + j] = bv[j]; si[t * NCLS + j] = bi[j]; }
  __syncthreads();
  for (int s = 128; s > 0; s >>= 1) {
    if (t < s) {
#pragma unroll
      for (int j = 0; j < NCLS; ++j) {
        const float v2 = sv[(t + s) * NCLS + j]; const int i2 = si[(t + s) * NCLS + j];
        const float v1 = sv[t * NCLS + j];       const int i1 = si[t * NCLS + j];
        if (v2 > v1 || (v2 == v1 && i2 < i1)) { sv[t * NCLS + j] = v2; si[t * NCLS + j] = i2; }
      }
    }
    __syncthreads();
  }
  if (t < NCLS) { pv[blockIdx.x * NCLS + t] = sv[t]; pi[blockIdx.x * NCLS + t] = si[t]; }
}

// ------------------------- one-pass softmax partials per block -------------
// Pm[b][j] = block max, Ps[b][j] = sum exp(x - block max). L2-hot re-read.
__global__ __launch_bounds__(256) void k_softpart(const float* __restrict__ logits,
                                                  float* __restrict__ Pm,
                                                  float* __restrict__ Ps) {
  __shared__ float sm[256 * NCLS];
  const int t = threadIdx.x;
  float m[NCLS];
#pragma unroll
  for (int j = 0; j < NCLS; ++j) m[j] = -3.4e38f;
  for (int n = blockIdx.x * 256 + t; n < NROWS; n += 128 * 256)
#pragma unroll
    for (int j = 0; j < NCLS; ++j) m[j] = fmaxf(m[j], logits[(size_t)n * NCLS + j]);
#pragma unroll
  for (int j = 0; j < NCLS; ++j) sm[t * NCLS + j] = m[j];
  __syncthreads();
  for (int s = 128; s > 0; s >>= 1) {
    if (t < s)
#pragma unroll
      for (int j = 0; j < NCLS; ++j)
        sm[t * NCLS + j] = fmaxf(sm[t * NCLS + j], sm[(t + s) * NCLS + j]);
    __syncthreads();
  }
  float mloc[NCLS];
#pragma unroll
  for (int j = 0; j < NCLS; ++j) mloc[j] = sm[j];
  __syncthreads();
  float s[NCLS];
#pragma unroll
  for (int j = 0; j < NCLS; ++j) s[j] = 0.f;
  for (int n = blockIdx.x * 256 + t; n < NROWS; n += 128 * 256)
#pragma unroll
    for (int j = 0; j < NCLS; ++j) s[j] += expf(logits[(size_t)n * NCLS + j] - mloc[j]);
#pragma unroll
  for (int j = 0; j < NCLS; ++j) sm[t * NCLS + j] = s[j];
  __syncthreads();
  for (int st = 128; st > 0; st >>= 1) {
    if (t < st)
#pragma unroll
      for (int j = 0; j < NCLS; ++j) sm[t * NCLS + j] += sm[(t + st) * NCLS + j];
    __syncthreads();
  }
  if (t < NCLS) { Pm[blockIdx.x * NCLS + t] = mloc[t]; Ps[blockIdx.x * NCLS + t] = sm[t]; }
}

// ------------------------- B-partials = A^T V, fused A-write + rescale-fin -
__global__ __launch_bounds__(256) void k_bpart(const float* __restrict__ logits,
                                               const float* __restrict__ Pm,
                                               const float* __restrict__ Ps,
                                               const u16* __restrict__ V,
                                               float* __restrict__ Aout,
                                               float* __restrict__ Pb) {
  __shared__ float sA[98 * NCLS];
  __shared__ float sM[NCLS], sR[NCLS];
  const int t = threadIdx.x;
  if (t < NCLS) {
    float M = -3.4e38f;
    for (int b = 0; b < 128; ++b) M = fmaxf(M, Pm[b * NCLS + t]);
    float S = 0.f;
    for (int b = 0; b < 128; ++b) S += Ps[b * NCLS + t] * expf(Pm[b * NCLS + t] - M);
    sM[t] = M; sR[t] = 1.0f / S;
  }
  __syncthreads();
  const int n0 = blockIdx.x * 98;
  int cnt = NROWS - n0;
  cnt = cnt < 0 ? 0 : (cnt > 98 ? 98 : cnt);
  for (int idx = t; idx < cnt * NCLS; idx += 256) {
    const int j = idx % NCLS;
    const float a = expf(logits[(size_t)n0 * NCLS + idx] - sM[j]) * sR[j];
    sA[idx] = a;
    Aout[(size_t)n0 * NCLS + idx] = a;
  }
  __syncthreads();
  float acc[NCLS][4] = {};
  for (int r = 0; r < cnt; ++r) {
    u16x4 vv = *(const u16x4*)&V[(size_t)(n0 + r) * DDIM + t * 4];
    const float f0 = bf2f(vv[0]), f1 = bf2f(vv[1]), f2 = bf2f(vv[2]), f3 = bf2f(vv[3]);
#pragma unroll
    for (int j = 0; j < NCLS; ++j) {
      const float a = sA[r * NCLS + j];
      acc[j][0] += a * f0; acc[j][1] += a * f1; acc[j][2] += a * f2; acc[j][3] += a * f3;
    }
  }
#pragma unroll
  for (int j = 0; j < NCLS; ++j) {
    f32x4 o = {acc[j][0], acc[j][1], acc[j][2], acc[j][3]};
    *(f32x4*)&Pb[((size_t)blockIdx.x * NCLS + j) * DDIM + t * 4] = o;
  }
}

__global__ void k_bred(const float* __restrict__ Pb, float* __restrict__ Bout) {
  const int idx = blockIdx.x * 256 + threadIdx.x;
  if (idx >= NCLS * DDIM) return;
  float s = 0.f;
  for (int p = 0; p < 512; ++p) s += Pb[(size_t)p * NCLS * DDIM + idx];
  Bout[idx] = s;
}

// ------------------------- C[o] = <B, head_w[o]> + head_b[o] ---------------
__global__ __launch_bounds__(256) void k_head(const float* __restrict__ Bmat,
                                              const float* __restrict__ hw,
                                              const float* __restrict__ hb,
                                              float* __restrict__ Cout) {
  const int o = blockIdx.x, t = threadIdx.x;
  float p = 0.f;
  for (int idx = t; idx < NCLS * DDIM; idx += 256)
    p += Bmat[idx] * hw[(size_t)o * NCLS * DDIM + idx];
#pragma unroll
  for (int m = 1; m < 64; m <<= 1) p += __shfl_xor(p, m, 64);
  __shared__ float w[4];
  if ((t & 63) == 0) w[t >> 6] = p;
  __syncthreads();
  if (t == 0) Cout[o] = w[0] + w[1] + w[2] + w[3] + hb[o];
}

// ---------------------------------------------------------------------------
extern "C" void kernel_launch(void* const* d_in, const int* in_sizes, int n_in,
                              void* d_out, int out_size, void* d_ws, size_t ws_size,
                              hipStream_t stream) {
  const float* features   = (const float*)d_in[0];
  const float* c_in       = (const float*)d_in[1];
  const float* key_w      = (const float*)d_in[2];
  const float* key_b      = (const float*)d_in[3];
  const float* key_g      = (const float*)d_in[4];
  const float* key_beta   = (const float*)d_in[5];
  const float* query_w    = (const float*)d_in[6];
  const float* query_b    = (const float*)d_in[7];
  const float* query_g    = (const float*)d_in[8];
  const float* query_beta = (const float*)d_in[9];
  const float* value_w    = (const float*)d_in[10];
  const float* value_b    = (const float*)d_in[11];
  const float* value_g    = (const float*)d_in[12];
  const float* value_beta = (const float*)d_in[13];
  const float* head_w     = (const float*)d_in[14];
  const float* head_b     = (const float*)d_in[15];

  char* ws = (char*)d_ws;
  const size_t SZB = (size_t)MP * DDIM * 2;             // 102,498,304 B
  u16* HbK  = (u16*)ws;                                 // [MP,1024]
  u16* Kb   = (u16*)(ws + SZB);                         // [MP,1024]
  u16* HbVQ = (u16*)(ws + 2 * SZB);                     // [MP,2048]
  u16* Vb   = Kb;                                       // reuse after VQ-GEMM
  size_t off = 4 * SZB;
  u16* Wk  = (u16*)(ws + off); off += (size_t)DDIM * DDIM * 2;
  u16* Wvq = (u16*)(ws + off); off += (size_t)2 * DDIM * DDIM * 2;
  float* logits = (float*)(ws + off); off += ((size_t)NROWS * NCLS * 4 + 255) & ~(size_t)255;
  float* Pb  = (float*)(ws + off); off += (size_t)512 * NCLS * DDIM * 4;
  u16* qm    = (u16*)(ws + off); off += ((size_t)NCLS * DDIM * 2 + 255) & ~(size_t)255;
  float* Pmax = (float*)(ws + off); off += ((size_t)128 * NCLS * 4 + 255) & ~(size_t)255;
  float* Psum = (float*)(ws + off); off += ((size_t)128 * NCLS * 4 + 255) & ~(size_t)255;
  float* argv = (float*)(ws + off); off += ((size_t)128 * NCLS * 4 + 255) & ~(size_t)255;
  int*   argi = (int*)  (ws + off); off += ((size_t)128 * NCLS * 4 + 255) & ~(size_t)255;

  float* Cout = (float*)d_out;                          // [7]
  float* Aout = Cout + NCLS;                            // [50000,7]
  float* Bout = Aout + (size_t)NROWS * NCLS;            // [7,1024]

  // argmax partials + weight converts
  k_arg1<<<128, 256, 0, stream>>>(c_in, argv, argi);
  k_convw<<<384, 256, 0, stream>>>(key_w, value_w, query_w, Wk, Wvq);

  // K chain: fp32-A GEMM (no convert pass), then LN
  k_gemm<1><<<3128, 256, 0, stream>>>(features, nullptr, Wk, HbK, 3, 1024);
  k_ln_k<<<MPD4, 256, 0, stream>>>(HbK, key_b, key_g, key_beta, Kb);

  // merged V|Q GEMM (bf16 A), q_max from HbVQ, merged LN (V + logits)
  k_gemm<0><<<6256, 256, 0, stream>>>(nullptr, Kb, Wvq, HbVQ, 4, 2048);
  k_qmax2<<<NCLS, 64, 0, stream>>>(argv, argi, HbVQ, query_b, query_g, query_beta, qm);
  k_ln_vq<<<2 * MPD4, 256, 0, stream>>>(HbVQ, value_b, value_g, value_beta,
                                        query_b, query_g, query_beta, qm, Vb, logits);

  // softmax over axis 0: one-pass partials, rescale-fin in consumer
  k_softpart<<<128, 256, 0, stream>>>(logits, Pmax, Psum);

  // B = A^T V (A materialized on the fly), head contraction
  k_bpart<<<512, 256, 0, stream>>>(logits, Pmax, Psum, Vb, Aout, Pb);
  k_bred<<<28, 256, 0, stream>>>(Pb, Bout);
  k_head<<<NCLS, 256, 0, stream>>>(Bout, head_w, head_b, Cout);
}

// Round 7
// 726.942 us; speedup vs baseline: 1.5569x; 1.0265x over previous
//
#include <hip/hip_runtime.h>

// ---------------------------------------------------------------------------
// AttDual round 7: VQ GEMM ported to 256x256 / BK=64 phased schedule (8 waves,
// raw s_barrier phases, counted waits only at iteration boundary, setprio
// around MFMA, conflict-free slot^row swizzle). K-chain keeps r6's fused
// fp32-A 128^2 GEMM. Tail identical to r6.
// ---------------------------------------------------------------------------

typedef unsigned short u16;
typedef __attribute__((ext_vector_type(8))) short          bf16x8;
typedef __attribute__((ext_vector_type(8))) unsigned short u16x8;
typedef __attribute__((ext_vector_type(4))) unsigned short u16x4;
typedef __attribute__((ext_vector_type(4))) float          f32x4;

#define DDIM  1024
#define NROWS 50000
#define MP    50176      // 196 * 256 padded rows (zeros)
#define NCLS  7
#define MPD4  12544      // MP/4

__device__ __forceinline__ u16 f2bf(float f) {          // RNE fp32 -> bf16
  unsigned u = __float_as_uint(f);
  u = (u + 0x7FFFu + ((u >> 16) & 1u)) >> 16;
  return (u16)u;
}
__device__ __forceinline__ float bf2f(u16 h) {
  return __uint_as_float(((unsigned)h) << 16);
}
__device__ __forceinline__ float gelu(float x) {
  return 0.5f * x * (1.0f + erff(x * 0.70710678118654752f));
}

__device__ __forceinline__ void load16_lds(const u16* g, u16* l) {
  __builtin_amdgcn_global_load_lds(
      (const __attribute__((address_space(1))) unsigned int*)(const void*)g,
      (__attribute__((address_space(3))) unsigned int*)(void*)l, 16, 0, 0);
}

#define MFMA_(a, b, c) __builtin_amdgcn_mfma_f32_16x16x32_bf16(a, b, c, 0, 0, 0)

// ------------------------- 3 weight matrices -> Wk, Wvq=concat(Wv,Wq) ------
__global__ __launch_bounds__(256) void k_convw(const float* __restrict__ kw,
                                               const float* __restrict__ vw,
                                               const float* __restrict__ qw,
                                               u16* __restrict__ Wk,
                                               u16* __restrict__ Wvq) {
  const int w = blockIdx.x >> 7;
  const int b = blockIdx.x & 127;
  const float* src = (w == 0) ? kw : (w == 1) ? vw : qw;
  u16* dst = (w == 0) ? Wk : (Wvq + (size_t)(w - 1) * DDIM * DDIM);
  for (int i = b * 256 + threadIdx.x; i < DDIM * DDIM / 8; i += 128 * 256) {
    const float4* p = (const float4*)(src + (size_t)i * 8);
    float4 f0 = p[0], f1 = p[1];
    u16x8 o;
    o[0] = f2bf(f0.x); o[1] = f2bf(f0.y); o[2] = f2bf(f0.z); o[3] = f2bf(f0.w);
    o[4] = f2bf(f1.x); o[5] = f2bf(f1.y); o[6] = f2bf(f1.z); o[7] = f2bf(f1.w);
    *(u16x8*)(dst + (size_t)i * 8) = o;
  }
}

// ------------------------- r6 128^2 GEMM (fp32-A path), K-chain only -------
template<int AFP32>
__global__ __launch_bounds__(256) void k_gemm(const float* __restrict__ Af,
                                              const u16* __restrict__ Ab,
                                              const u16* __restrict__ B,
                                              u16* __restrict__ C,
                                              int lnn, int ldc) {
  __shared__ __align__(16) u16 As[128 * 32];
  __shared__ __align__(16) u16 Bs[128 * 32];
  const int tid  = threadIdx.x;
  const int lane = tid & 63;
  const int cpx = gridDim.x >> 3;                       // nwg % 8 == 0
  const int v   = (blockIdx.x & 7) * cpx + (blockIdx.x >> 3);
  const int m0 = (v >> lnn) * 128;
  const int n0 = (v & ((1 << lnn) - 1)) * 128;
  const int wid = tid >> 6;
  const int wr = (wid >> 1) * 64;
  const int wc = (wid & 1) * 64;

  const int rA = tid >> 2;                              // 0..63
  const int slotl = tid & 3;                            // logical 8-elem slot
  const int swz = (rA >> 1) & 3;
  const int cA = ((slotl ^ swz) << 3);                  // swizzled source slot
  const u16* Bp0 = B + (size_t)(n0 + rA) * DDIM + cA;
  const u16* Bp1 = Bp0 + (size_t)64 * DDIM;
  const u16* Ap0 = nullptr; const u16* Ap1 = nullptr;
  const float* Fp0 = nullptr; const float* Fp1 = nullptr;
  bool av0 = false, av1 = false;
  if (AFP32) {
    av0 = (m0 + rA) < NROWS;
    av1 = (m0 + rA + 64) < NROWS;
    Fp0 = Af + (size_t)(m0 + rA) * DDIM + slotl * 8;
    Fp1 = Fp0 + (size_t)64 * DDIM;
  } else {
    Ap0 = Ab + (size_t)(m0 + rA) * DDIM + cA;
    Ap1 = Ap0 + (size_t)64 * DDIM;
  }
  const int wbase = wid * 64;
  u16* AsD0 = &As[(wbase)       * 8];
  u16* AsD1 = &As[(wbase + 256) * 8];
  u16* BsD0 = &Bs[(wbase)       * 8];
  u16* BsD1 = &Bs[(wbase + 256) * 8];
  u16* AsW0 = &As[rA * 32 + cA];
  u16* AsW1 = &As[(rA + 64) * 32 + cA];

  f32x4 acc[4][4] = {};
  const int fr = lane & 15;
  const int T  = lane >> 4;

  for (int k0 = 0; k0 < DDIM; k0 += 32) {
    float4 fa0, fb0, fa1, fb1;
    if (AFP32) {
      if (av0) { fa0 = *(const float4*)(Fp0 + k0); fb0 = *(const float4*)(Fp0 + k0 + 4); }
      if (av1) { fa1 = *(const float4*)(Fp1 + k0); fb1 = *(const float4*)(Fp1 + k0 + 4); }
    }
    __syncthreads();
    if (AFP32) {
      u16x8 o0 = {0,0,0,0,0,0,0,0}, o1 = {0,0,0,0,0,0,0,0};
      if (av0) {
        o0[0]=f2bf(fa0.x); o0[1]=f2bf(fa0.y); o0[2]=f2bf(fa0.z); o0[3]=f2bf(fa0.w);
        o0[4]=f2bf(fb0.x); o0[5]=f2bf(fb0.y); o0[6]=f2bf(fb0.z); o0[7]=f2bf(fb0.w);
      }
      if (av1) {
        o1[0]=f2bf(fa1.x); o1[1]=f2bf(fa1.y); o1[2]=f2bf(fa1.z); o1[3]=f2bf(fa1.w);
        o1[4]=f2bf(fb1.x); o1[5]=f2bf(fb1.y); o1[6]=f2bf(fb1.z); o1[7]=f2bf(fb1.w);
      }
      *(u16x8*)AsW0 = o0;
      *(u16x8*)AsW1 = o1;
    } else {
      load16_lds(Ap0 + k0, AsD0);
      load16_lds(Ap1 + k0, AsD1);
    }
    load16_lds(Bp0 + k0, BsD0);
    load16_lds(Bp1 + k0, BsD1);
    __syncthreads();
    bf16x8 a[4], b[4];
#pragma unroll
    for (int i = 0; i < 4; ++i) {
      const int R = wr + i * 16 + fr;
      a[i] = *(const bf16x8*)&As[R * 32 + ((T ^ ((R >> 1) & 3)) << 3)];
    }
#pragma unroll
    for (int j = 0; j < 4; ++j) {
      const int R = wc + j * 16 + fr;
      b[j] = *(const bf16x8*)&Bs[R * 32 + ((T ^ ((R >> 1) & 3)) << 3)];
    }
#pragma unroll
    for (int i = 0; i < 4; ++i)
#pragma unroll
      for (int j = 0; j < 4; ++j)
        acc[i][j] = MFMA_(a[i], b[j], acc[i][j]);
  }

  const int orow = (lane >> 4) * 4;
  const int ocol = lane & 15;
#pragma unroll
  for (int i = 0; i < 4; ++i)
#pragma unroll
    for (int j = 0; j < 4; ++j) {
      const size_t base = (size_t)(m0 + wr + i * 16 + orow) * ldc + (n0 + wc + j * 16 + ocol);
#pragma unroll
      for (int r = 0; r < 4; ++r)
        C[base + (size_t)r * ldc] = f2bf(acc[i][j][r]);
    }
}

// ------------------------- 256^2 phased GEMM (VQ: bf16 A, bf16 B) ----------
// C[m,n] = sum_k A[m,k]*B[n,k].  M=50176 (196 tiles) x N=2048 (8 tiles).
// 8 waves: wr=wid>>2 (A-half), wc=wid&3 (64-col group, B-half wc>>1).
// LDS: A,B x 2 bufs x 2 halves x (128x64 bf16) = 128 KiB (dynamic).
// Per K-tile: 4 phases {stage | ds_read | setprio+16 MFMA} + raw s_barrier;
// waits: lgkmcnt(0)+vmcnt(0) only at the iteration-final barrier.
__global__ __launch_bounds__(512, 2) void k_gemm256(const u16* __restrict__ A,
                                                    const u16* __restrict__ Bw,
                                                    u16* __restrict__ C) {
  extern __shared__ __align__(16) u16 smem[];
  u16* Abase = smem;                 // [2][2][8192]
  u16* Bbase = smem + 32768;         // [2][2][8192]
  const int tid  = threadIdx.x;
  const int lane = tid & 63;
  const int wid  = tid >> 6;
  const int wr = wid >> 2;           // 0..1  : A half (128 rows)
  const int wc = wid & 3;            // 0..3  : 64-col group
  const int bh = wc >> 1;            // B half this wave reads
  const int bl = (wc & 1) * 64;      // local n-row base within B half
  const int fr = lane & 15;
  const int T  = lane >> 4;
  const int v  = (blockIdx.x & 7) * 196 + (blockIdx.x >> 3);   // 1568 blocks
  const int m0 = (v >> 3) * 256;
  const int n0 = (v & 7) * 256;

  f32x4 acc[8][4] = {};

#define STAGE_A(KT, BB) do {                                                   \
    _Pragma("unroll") for (int h_ = 0; h_ < 2; ++h_)                           \
      _Pragma("unroll") for (int l_ = 0; l_ < 2; ++l_) {                       \
        const int s_ = l_ * 512 + tid;                                         \
        const int r_ = s_ >> 3;                                                \
        const int c_ = (s_ & 7) ^ (r_ & 7);                                    \
        load16_lds(A + (size_t)(m0 + h_ * 128 + r_) * DDIM + (KT) * 64 + c_ * 8, \
                   Abase + ((BB) * 2 + h_) * 8192 + s_ * 8);                   \
      } } while (0)

#define STAGE_B(KT, BB) do {                                                   \
    _Pragma("unroll") for (int h_ = 0; h_ < 2; ++h_)                           \
      _Pragma("unroll") for (int l_ = 0; l_ < 2; ++l_) {                       \
        const int s_ = l_ * 512 + tid;                                         \
        const int r_ = s_ >> 3;                                                \
        const int c_ = (s_ & 7) ^ (r_ & 7);                                    \
        load16_lds(Bw + (size_t)(n0 + h_ * 128 + r_) * DDIM + (KT) * 64 + c_ * 8, \
                   Bbase + ((BB) * 2 + h_) * 8192 + s_ * 8);                   \
      } } while (0)

#define PHASE_A(p) do {                                                        \
    bf16x8 afr[4];                                                             \
    _Pragma("unroll") for (int ks = 0; ks < 2; ++ks)                           \
      _Pragma("unroll") for (int ii = 0; ii < 2; ++ii) {                       \
        const int R = ((p) * 2 + ii) * 16 + fr;                                \
        afr[ks * 2 + ii] = *(const bf16x8*)&Ap[R * 64 + (((ks * 4 + T) ^ (R & 7)) << 3)]; \
      }                                                                        \
    __builtin_amdgcn_s_setprio(1);                                             \
    _Pragma("unroll") for (int ks = 0; ks < 2; ++ks)                           \
      _Pragma("unroll") for (int ii = 0; ii < 2; ++ii)                         \
        _Pragma("unroll") for (int j = 0; j < 4; ++j)                          \
          acc[(p) * 2 + ii][j] = MFMA_(afr[ks * 2 + ii], bfr[ks * 4 + j],      \
                                       acc[(p) * 2 + ii][j]);                  \
    __builtin_amdgcn_s_setprio(0);                                             \
  } while (0)

#define BARP() asm volatile("s_barrier" ::: "memory")

  // prologue: stage kt=0 into buf 0, drain, barrier
  STAGE_A(0, 0);
  STAGE_B(0, 0);
  asm volatile("s_waitcnt vmcnt(0)\n\ts_barrier" ::: "memory");

  for (int kt = 0; kt < 16; ++kt) {
    const int b = kt & 1;
    const u16* Ap = Abase + (b * 2 + wr) * 8192;
    const u16* Bp = Bbase + (b * 2 + bh) * 8192;
    const bool st = kt < 15;
    bf16x8 bfr[8];
    // PH1: stage A(kt+1) into dead buf; read all B-frags + A row-pair 0
    if (st) STAGE_A(kt + 1, b ^ 1);
#pragma unroll
    for (int ks = 0; ks < 2; ++ks)
#pragma unroll
      for (int j = 0; j < 4; ++j) {
        const int R = bl + j * 16 + fr;
        bfr[ks * 4 + j] = *(const bf16x8*)&Bp[R * 64 + (((ks * 4 + T) ^ (R & 7)) << 3)];
      }
    PHASE_A(0);
    BARP();
    // PH2: stage B(kt+1); row-pair 1
    if (st) STAGE_B(kt + 1, b ^ 1);
    PHASE_A(1);
    BARP();
    // PH3
    PHASE_A(2);
    BARP();
    // PH4: iteration-final: all ds_reads drained, incoming tile landed
    PHASE_A(3);
    if (st)
      asm volatile("s_waitcnt vmcnt(0) lgkmcnt(0)\n\ts_barrier" ::: "memory");
  }
#undef STAGE_A
#undef STAGE_B
#undef PHASE_A
#undef BARP

  // epilogue: C write (ldc = 2048)
#pragma unroll
  for (int i = 0; i < 8; ++i)
#pragma unroll
    for (int j = 0; j < 4; ++j) {
      const size_t base = (size_t)(m0 + wr * 128 + i * 16 + T * 4) * 2048
                        + (n0 + wc * 64 + j * 16 + fr);
#pragma unroll
      for (int r = 0; r < 4; ++r)
        C[base + (size_t)r * 2048] = f2bf(acc[i][j][r]);
    }
}

// ------------------------- bias + LN + GELU for K (zero-pads rows) ---------
__global__ __launch_bounds__(256) void k_ln_k(const u16* __restrict__ h,
                                              const float* __restrict__ bias,
                                              const float* __restrict__ g,
                                              const float* __restrict__ beta,
                                              u16* __restrict__ out) {
  const int lane = threadIdx.x & 63;
  const int row = blockIdx.x * 4 + (threadIdx.x >> 6);
  const int c0 = lane * 8;
  u16x8* op0 = (u16x8*)(out + (size_t)row * DDIM + c0);
  u16x8* op1 = (u16x8*)(out + (size_t)row * DDIM + 512 + c0);
  if (row >= NROWS) {
    u16x8 z = {0, 0, 0, 0, 0, 0, 0, 0};
    *op0 = z; *op1 = z;
    return;
  }
  u16x8 h0 = *(const u16x8*)(h + (size_t)row * DDIM + c0);
  u16x8 h1 = *(const u16x8*)(h + (size_t)row * DDIM + 512 + c0);
  float4 a0 = *(const float4*)(bias + c0), a1 = *(const float4*)(bias + c0 + 4);
  float4 a2 = *(const float4*)(bias + 512 + c0), a3 = *(const float4*)(bias + 512 + c0 + 4);
  const float ba[8] = {a0.x, a0.y, a0.z, a0.w, a1.x, a1.y, a1.z, a1.w};
  const float bb[8] = {a2.x, a2.y, a2.z, a2.w, a3.x, a3.y, a3.z, a3.w};
  float v0[8], v1[8];
  float s1 = 0.f, s2 = 0.f;
#pragma unroll
  for (int e = 0; e < 8; ++e) {
    v0[e] = bf2f(h0[e]) + ba[e];
    v1[e] = bf2f(h1[e]) + bb[e];
    s1 += v0[e] + v1[e];
    s2 += v0[e] * v0[e] + v1[e] * v1[e];
  }
#pragma unroll
  for (int m = 1; m < 64; m <<= 1) {
    s1 += __shfl_xor(s1, m, 64);
    s2 += __shfl_xor(s2, m, 64);
  }
  const float mu = s1 * (1.0f / 1024.0f);
  const float var = s2 * (1.0f / 1024.0f) - mu * mu;
  const float rs = rsqrtf(var + 1e-5f);
  float4 g0 = *(const float4*)(g + c0), g1 = *(const float4*)(g + c0 + 4);
  float4 g2 = *(const float4*)(g + 512 + c0), g3 = *(const float4*)(g + 512 + c0 + 4);
  float4 t0 = *(const float4*)(beta + c0), t1 = *(const float4*)(beta + c0 + 4);
  float4 t2 = *(const float4*)(beta + 512 + c0), t3 = *(const float4*)(beta + 512 + c0 + 4);
  const float ga[8] = {g0.x, g0.y, g0.z, g0.w, g1.x, g1.y, g1.z, g1.w};
  const float gb[8] = {g2.x, g2.y, g2.z, g2.w, g3.x, g3.y, g3.z, g3.w};
  const float ta[8] = {t0.x, t0.y, t0.z, t0.w, t1.x, t1.y, t1.z, t1.w};
  const float tb[8] = {t2.x, t2.y, t2.z, t2.w, t3.x, t3.y, t3.z, t3.w};
  u16x8 o0, o1;
#pragma unroll
  for (int e = 0; e < 8; ++e) {
    o0[e] = f2bf(gelu((v0[e] - mu) * rs * ga[e] + ta[e]));
    o1[e] = f2bf(gelu((v1[e] - mu) * rs * gb[e] + tb[e]));
  }
  *op0 = o0; *op1 = o1;
}

// ------------------------- q_max from HbVQ rows (fin of argmax inside) -----
__global__ __launch_bounds__(64) void k_qmax2(const float* __restrict__ argv,
                                              const int* __restrict__ argi,
                                              const u16* __restrict__ hvq,
                                              const float* __restrict__ qb,
                                              const float* __restrict__ qg,
                                              const float* __restrict__ qbeta,
                                              u16* __restrict__ qm) {
  const int j = blockIdx.x;
  const int lane = threadIdx.x;
  float bv = -3.4e38f; int bi = 0x7fffffff;
  for (int p = lane; p < 128; p += 64) {
    const float v = argv[p * NCLS + j];
    const int   i = argi[p * NCLS + j];
    if (v > bv || (v == bv && i < bi)) { bv = v; bi = i; }
  }
#pragma unroll
  for (int m = 1; m < 64; m <<= 1) {
    const float ov = __shfl_xor(bv, m, 64);
    const int   oi = __shfl_xor(bi, m, 64);
    if (ov > bv || (ov == bv && oi < bi)) { bv = ov; bi = oi; }
  }
  const int row = bi;
  const int c0 = lane * 8;
  const u16* hp = hvq + (size_t)row * 2048 + DDIM;      // Q-half
  u16x8 h0 = *(const u16x8*)(hp + c0);
  u16x8 h1 = *(const u16x8*)(hp + 512 + c0);
  float v0[8], v1[8];
  float s1 = 0.f, s2 = 0.f;
#pragma unroll
  for (int e = 0; e < 8; ++e) {
    v0[e] = bf2f(h0[e]) + qb[c0 + e];
    v1[e] = bf2f(h1[e]) + qb[512 + c0 + e];
    s1 += v0[e] + v1[e];
    s2 += v0[e] * v0[e] + v1[e] * v1[e];
  }
#pragma unroll
  for (int m = 1; m < 64; m <<= 1) {
    s1 += __shfl_xor(s1, m, 64);
    s2 += __shfl_xor(s2, m, 64);
  }
  const float mu = s1 * (1.0f / 1024.0f);
  const float var = s2 * (1.0f / 1024.0f) - mu * mu;
  const float rs = rsqrtf(var + 1e-5f);
  u16x8 o0, o1;
#pragma unroll
  for (int e = 0; e < 8; ++e) {
    o0[e] = f2bf(gelu((v0[e] - mu) * rs * qg[c0 + e] + qbeta[c0 + e]));
    o1[e] = f2bf(gelu((v1[e] - mu) * rs * qg[512 + c0 + e] + qbeta[512 + c0 + e]));
  }
  *(u16x8*)(qm + (size_t)j * DDIM + c0) = o0;
  *(u16x8*)(qm + (size_t)j * DDIM + 512 + c0) = o1;
}

// ------------------------- merged V/Q LN; Q-half emits logits only ---------
__global__ __launch_bounds__(256) void k_ln_vq(const u16* __restrict__ h,
                                               const float* __restrict__ v_b,
                                               const float* __restrict__ v_g,
                                               const float* __restrict__ v_beta,
                                               const float* __restrict__ q_b,
                                               const float* __restrict__ q_g,
                                               const float* __restrict__ q_beta,
                                               const u16* __restrict__ qm,
                                               u16* __restrict__ V,
                                               float* __restrict__ logits) {
  __shared__ __align__(16) u16 sqm[NCLS * DDIM];        // 14 KB
  const int tid = threadIdx.x;
  const int lane = tid & 63;
  const int half = (blockIdx.x >= MPD4) ? 1 : 0;
  const int rb = half ? (blockIdx.x - MPD4) : blockIdx.x;
  const int row = rb * 4 + (tid >> 6);
  if (half) {
    for (int i = tid; i < NCLS * DDIM / 8; i += 256)
      *(u16x8*)&sqm[i * 8] = *(const u16x8*)&qm[i * 8];
    __syncthreads();
  }
  if (row >= NROWS) return;                             // no sync after this
  const float* bias = half ? q_b : v_b;
  const float* gain = half ? q_g : v_g;
  const float* bet  = half ? q_beta : v_beta;
  const int c0 = lane * 8;
  const u16* hp = h + (size_t)row * 2048 + (size_t)half * DDIM;
  u16x8 h0 = *(const u16x8*)(hp + c0);
  u16x8 h1 = *(const u16x8*)(hp + 512 + c0);
  float4 a0 = *(const float4*)(bias + c0), a1 = *(const float4*)(bias + c0 + 4);
  float4 a2 = *(const float4*)(bias + 512 + c0), a3 = *(const float4*)(bias + 512 + c0 + 4);
  const float ba[8] = {a0.x, a0.y, a0.z, a0.w, a1.x, a1.y, a1.z, a1.w};
  const float bb[8] = {a2.x, a2.y, a2.z, a2.w, a3.x, a3.y, a3.z, a3.w};
  float v0[8], v1[8];
  float s1 = 0.f, s2 = 0.f;
#pragma unroll
  for (int e = 0; e < 8; ++e) {
    v0[e] = bf2f(h0[e]) + ba[e];
    v1[e] = bf2f(h1[e]) + bb[e];
    s1 += v0[e] + v1[e];
    s2 += v0[e] * v0[e] + v1[e] * v1[e];
  }
#pragma unroll
  for (int m = 1; m < 64; m <<= 1) {
    s1 += __shfl_xor(s1, m, 64);
    s2 += __shfl_xor(s2, m, 64);
  }
  const float mu = s1 * (1.0f / 1024.0f);
  const float var = s2 * (1.0f / 1024.0f) - mu * mu;
  const float rs = rsqrtf(var + 1e-5f);
  float4 g0 = *(const float4*)(gain + c0), g1 = *(const float4*)(gain + c0 + 4);
  float4 g2 = *(const float4*)(gain + 512 + c0), g3 = *(const float4*)(gain + 512 + c0 + 4);
  float4 t0 = *(const float4*)(bet + c0), t1 = *(const float4*)(bet + c0 + 4);
  float4 t2 = *(const float4*)(bet + 512 + c0), t3 = *(const float4*)(bet + 512 + c0 + 4);
  const float ga[8] = {g0.x, g0.y, g0.z, g0.w, g1.x, g1.y, g1.z, g1.w};
  const float gb[8] = {g2.x, g2.y, g2.z, g2.w, g3.x, g3.y, g3.z, g3.w};
  const float ta[8] = {t0.x, t0.y, t0.z, t0.w, t1.x, t1.y, t1.z, t1.w};
  const float tb[8] = {t2.x, t2.y, t2.z, t2.w, t3.x, t3.y, t3.z, t3.w};
  float y0[8], y1[8];
#pragma unroll
  for (int e = 0; e < 8; ++e) {
    y0[e] = gelu((v0[e] - mu) * rs * ga[e] + ta[e]);
    y1[e] = gelu((v1[e] - mu) * rs * gb[e] + tb[e]);
  }
  if (half == 0) {
    u16x8 o0, o1;
#pragma unroll
    for (int e = 0; e < 8; ++e) { o0[e] = f2bf(y0[e]); o1[e] = f2bf(y1[e]); }
    *(u16x8*)(V + (size_t)row * DDIM + c0) = o0;
    *(u16x8*)(V + (size_t)row * DDIM + 512 + c0) = o1;
  } else {
#pragma unroll
    for (int j = 0; j < NCLS; ++j) {
      u16x8 m0 = *(const u16x8*)&sqm[j * DDIM + c0];
      u16x8 m1 = *(const u16x8*)&sqm[j * DDIM + 512 + c0];
      float p = 0.f;
#pragma unroll
      for (int e = 0; e < 8; ++e) p += y0[e] * bf2f(m0[e]) + y1[e] * bf2f(m1[e]);
#pragma unroll
      for (int m = 1; m < 64; m <<= 1) p += __shfl_xor(p, m, 64);
      if (lane == 0) logits[(size_t)row * NCLS + j] = p * 0.03125f;
    }
  }
}

// ------------------------- argmax partials (first-index) -------------------
__global__ __launch_bounds__(256) void k_arg1(const float* __restrict__ c,
                                              float* __restrict__ pv,
                                              int* __restrict__ pi) {
  __shared__ float sv[256 * NCLS];
  __shared__ int   si[256 * NCLS];
  const int t = threadIdx.x;
  float bv[NCLS]; int bi[NCLS];
#pragma unroll
  for (int j = 0; j < NCLS; ++j) { bv[j] = -3.4e38f; bi[j] = 0x7fffffff; }
  for (int n = blockIdx.x * 256 + t; n < NROWS; n += 128 * 256) {
#pragma unroll
    for (int j = 0; j < NCLS; ++j) {
      const float v = c[(size_t)n * NCLS + j];
      if (v > bv[j]) { bv[j] = v; bi[j] = n; }
    }
  }
#pragma unroll
  for (int j = 0; j < NCLS; ++j) { sv[t * NCLS + j] = bv[j]; si[t * NCLS + j] = bi[j]; }
  __syncthreads();
  for (int s = 128; s > 0; s >>= 1) {
    if (t < s) {
#pragma unroll
      for (int j = 0; j < NCLS; ++j) {
        const float v2 = sv[(t + s) * NCLS + j]; const int i2 = si[(t + s) * NCLS + j];
        const float v1 = sv[t * NCLS + j];       const int i1 = si[t * NCLS + j];
        if (v2 > v1 || (v2 == v1 && i2 < i1)) { sv[t * NCLS + j] = v2; si[t * NCLS + j] = i2; }
      }
    }
    __syncthreads();
  }
  if (t < NCLS) { pv[blockIdx.x * NCLS + t] = sv[t]; pi[blockIdx.x * NCLS + t] = si[t]; }
}

// ------------------------- one-pass softmax partials per block -------------
__global__ __launch_bounds__(256) void k_softpart(const float* __restrict__ logits,
                                                  float* __restrict__ Pm,
                                                  float* __restrict__ Ps) {
  __shared__ float sm[256 * NCLS];
  const int t = threadIdx.x;
  float m[NCLS];
#pragma unroll
  for (int j = 0; j < NCLS; ++j) m[j] = -3.4e38f;
  for (int n = blockIdx.x * 256 + t; n < NROWS; n += 128 * 256)
#pragma unroll
    for (int j = 0; j < NCLS; ++j) m[j] = fmaxf(m[j], logits[(size_t)n * NCLS + j]);
#pragma unroll
  for (int j = 0; j < NCLS; ++j) sm[t * NCLS + j] = m[j];
  __syncthreads();
  for (int s = 128; s > 0; s >>= 1) {
    if (t < s)
#pragma unroll
      for (int j = 0; j < NCLS; ++j)
        sm[t * NCLS + j] = fmaxf(sm[t * NCLS + j], sm[(t + s) * NCLS + j]);
    __syncthreads();
  }
  float mloc[NCLS];
#pragma unroll
  for (int j = 0; j < NCLS; ++j) mloc[j] = sm[j];
  __syncthreads();
  float s[NCLS];
#pragma unroll
  for (int j = 0; j < NCLS; ++j) s[j] = 0.f;
  for (int n = blockIdx.x * 256 + t; n < NROWS; n += 128 * 256)
#pragma unroll
    for (int j = 0; j < NCLS; ++j) s[j] += expf(logits[(size_t)n * NCLS + j] - mloc[j]);
#pragma unroll
  for (int j = 0; j < NCLS; ++j) sm[t * NCLS + j] = s[j];
  __syncthreads();
  for (int st = 128; st > 0; st >>= 1) {
    if (t < st)
#pragma unroll
      for (int j = 0; j < NCLS; ++j) sm[t * NCLS + j] += sm[(t + st) * NCLS + j];
    __syncthreads();
  }
  if (t < NCLS) { Pm[blockIdx.x * NCLS + t] = mloc[t]; Ps[blockIdx.x * NCLS + t] = sm[t]; }
}

// ------------------------- B-partials = A^T V, fused A-write + rescale-fin -
__global__ __launch_bounds__(256) void k_bpart(const float* __restrict__ logits,
                                               const float* __restrict__ Pm,
                                               const float* __restrict__ Ps,
                                               const u16* __restrict__ V,
                                               float* __restrict__ Aout,
                                               float* __restrict__ Pb) {
  __shared__ float sA[98 * NCLS];
  __shared__ float sM[NCLS], sR[NCLS];
  const int t = threadIdx.x;
  if (t < NCLS) {
    float M = -3.4e38f;
    for (int b = 0; b < 128; ++b) M = fmaxf(M, Pm[b * NCLS + t]);
    float S = 0.f;
    for (int b = 0; b < 128; ++b) S += Ps[b * NCLS + t] * expf(Pm[b * NCLS + t] - M);
    sM[t] = M; sR[t] = 1.0f / S;
  }
  __syncthreads();
  const int n0 = blockIdx.x * 98;
  int cnt = NROWS - n0;
  cnt = cnt < 0 ? 0 : (cnt > 98 ? 98 : cnt);
  for (int idx = t; idx < cnt * NCLS; idx += 256) {
    const int j = idx % NCLS;
    const float a = expf(logits[(size_t)n0 * NCLS + idx] - sM[j]) * sR[j];
    sA[idx] = a;
    Aout[(size_t)n0 * NCLS + idx] = a;
  }
  __syncthreads();
  float acc[NCLS][4] = {};
  for (int r = 0; r < cnt; ++r) {
    u16x4 vv = *(const u16x4*)&V[(size_t)(n0 + r) * DDIM + t * 4];
    const float f0 = bf2f(vv[0]), f1 = bf2f(vv[1]), f2 = bf2f(vv[2]), f3 = bf2f(vv[3]);
#pragma unroll
    for (int j = 0; j < NCLS; ++j) {
      const float a = sA[r * NCLS + j];
      acc[j][0] += a * f0; acc[j][1] += a * f1; acc[j][2] += a * f2; acc[j][3] += a * f3;
    }
  }
#pragma unroll
  for (int j = 0; j < NCLS; ++j) {
    f32x4 o = {acc[j][0], acc[j][1], acc[j][2], acc[j][3]};
    *(f32x4*)&Pb[((size_t)blockIdx.x * NCLS + j) * DDIM + t * 4] = o;
  }
}

__global__ void k_bred(const float* __restrict__ Pb, float* __restrict__ Bout) {
  const int idx = blockIdx.x * 256 + threadIdx.x;
  if (idx >= NCLS * DDIM) return;
  float s = 0.f;
  for (int p = 0; p < 512; ++p) s += Pb[(size_t)p * NCLS * DDIM + idx];
  Bout[idx] = s;
}

// ------------------------- C[o] = <B, head_w[o]> + head_b[o] ---------------
__global__ __launch_bounds__(256) void k_head(const float* __restrict__ Bmat,
                                              const float* __restrict__ hw,
                                              const float* __restrict__ hb,
                                              float* __restrict__ Cout) {
  const int o = blockIdx.x, t = threadIdx.x;
  float p = 0.f;
  for (int idx = t; idx < NCLS * DDIM; idx += 256)
    p += Bmat[idx] * hw[(size_t)o * NCLS * DDIM + idx];
#pragma unroll
  for (int m = 1; m < 64; m <<= 1) p += __shfl_xor(p, m, 64);
  __shared__ float w[4];
  if ((t & 63) == 0) w[t >> 6] = p;
  __syncthreads();
  if (t == 0) Cout[o] = w[0] + w[1] + w[2] + w[3] + hb[o];
}

// ---------------------------------------------------------------------------
extern "C" void kernel_launch(void* const* d_in, const int* in_sizes, int n_in,
                              void* d_out, int out_size, void* d_ws, size_t ws_size,
                              hipStream_t stream) {
  const float* features   = (const float*)d_in[0];
  const float* c_in       = (const float*)d_in[1];
  const float* key_w      = (const float*)d_in[2];
  const float* key_b      = (const float*)d_in[3];
  const float* key_g      = (const float*)d_in[4];
  const float* key_beta   = (const float*)d_in[5];
  const float* query_w    = (const float*)d_in[6];
  const float* query_b    = (const float*)d_in[7];
  const float* query_g    = (const float*)d_in[8];
  const float* query_beta = (const float*)d_in[9];
  const float* value_w    = (const float*)d_in[10];
  const float* value_b    = (const float*)d_in[11];
  const float* value_g    = (const float*)d_in[12];
  const float* value_beta = (const float*)d_in[13];
  const float* head_w     = (const float*)d_in[14];
  const float* head_b     = (const float*)d_in[15];

  char* ws = (char*)d_ws;
  const size_t SZB = (size_t)MP * DDIM * 2;             // 102,760,448 B
  u16* HbK  = (u16*)ws;                                 // [MP,1024]
  u16* Kb   = (u16*)(ws + SZB);                         // [MP,1024]
  u16* HbVQ = (u16*)(ws + 2 * SZB);                     // [MP,2048]
  u16* Vb   = Kb;                                       // reuse after VQ-GEMM
  size_t off = 4 * SZB;
  u16* Wk  = (u16*)(ws + off); off += (size_t)DDIM * DDIM * 2;
  u16* Wvq = (u16*)(ws + off); off += (size_t)2 * DDIM * DDIM * 2;
  float* logits = (float*)(ws + off); off += ((size_t)NROWS * NCLS * 4 + 255) & ~(size_t)255;
  float* Pb  = (float*)(ws + off); off += (size_t)512 * NCLS * DDIM * 4;
  u16* qm    = (u16*)(ws + off); off += ((size_t)NCLS * DDIM * 2 + 255) & ~(size_t)255;
  float* Pmax = (float*)(ws + off); off += ((size_t)128 * NCLS * 4 + 255) & ~(size_t)255;
  float* Psum = (float*)(ws + off); off += ((size_t)128 * NCLS * 4 + 255) & ~(size_t)255;
  float* argv = (float*)(ws + off); off += ((size_t)128 * NCLS * 4 + 255) & ~(size_t)255;
  int*   argi = (int*)  (ws + off); off += ((size_t)128 * NCLS * 4 + 255) & ~(size_t)255;

  float* Cout = (float*)d_out;                          // [7]
  float* Aout = Cout + NCLS;                            // [50000,7]
  float* Bout = Aout + (size_t)NROWS * NCLS;            // [7,1024]

  // argmax partials + weight converts
  k_arg1<<<128, 256, 0, stream>>>(c_in, argv, argi);
  k_convw<<<384, 256, 0, stream>>>(key_w, value_w, query_w, Wk, Wvq);

  // K chain: fp32-A GEMM (no convert pass), then LN (zero-pads to MP)
  k_gemm<1><<<3136, 256, 0, stream>>>(features, nullptr, Wk, HbK, 3, 1024);
  k_ln_k<<<MPD4, 256, 0, stream>>>(HbK, key_b, key_g, key_beta, Kb);

  // merged V|Q GEMM: 256^2 phased kernel (196 x 8 tiles, 128 KiB dynamic LDS)
  k_gemm256<<<1568, 512, 131072, stream>>>(Kb, Wvq, HbVQ);
  k_qmax2<<<NCLS, 64, 0, stream>>>(argv, argi, HbVQ, query_b, query_g, query_beta, qm);
  k_ln_vq<<<2 * MPD4, 256, 0, stream>>>(HbVQ, value_b, value_g, value_beta,
                                        query_b, query_g, query_beta, qm, Vb, logits);

  // softmax over axis 0: one-pass partials, rescale-fin in consumer
  k_softpart<<<128, 256, 0, stream>>>(logits, Pmax, Psum);

  // B = A^T V (A materialized on the fly), head contraction
  k_bpart<<<512, 256, 0, stream>>>(logits, Pmax, Psum, Vb, Aout, Pb);
  k_bred<<<28, 256, 0, stream>>>(Pb, Bout);
  k_head<<<NCLS, 256, 0, stream>>>(Bout, head_w, head_b, Cout);
}

// Round 8
// 726.502 us; speedup vs baseline: 1.5578x; 1.0006x over previous
//
#include <hip/hip_runtime.h>

// ---------------------------------------------------------------------------
// AttDual round 7: VQ GEMM ported to 256x256 / BK=64 phased schedule (8 waves,
// raw s_barrier phases, counted waits only at iteration boundary, setprio
// around MFMA, conflict-free slot^row swizzle). K-chain keeps r6's fused
// fp32-A 128^2 GEMM. Tail identical to r6.
// ---------------------------------------------------------------------------

typedef unsigned short u16;
typedef __attribute__((ext_vector_type(8))) short          bf16x8;
typedef __attribute__((ext_vector_type(8))) unsigned short u16x8;
typedef __attribute__((ext_vector_type(4))) unsigned short u16x4;
typedef __attribute__((ext_vector_type(4))) float          f32x4;

#define DDIM  1024
#define NROWS 50000
#define MP    50176      // 196 * 256 padded rows (zeros)
#define NCLS  7
#define MPD4  12544      // MP/4

__device__ __forceinline__ u16 f2bf(float f) {          // RNE fp32 -> bf16
  unsigned u = __float_as_uint(f);
  u = (u + 0x7FFFu + ((u >> 16) & 1u)) >> 16;
  return (u16)u;
}
__device__ __forceinline__ float bf2f(u16 h) {
  return __uint_as_float(((unsigned)h) << 16);
}
__device__ __forceinline__ float gelu(float x) {
  return 0.5f * x * (1.0f + erff(x * 0.70710678118654752f));
}

__device__ __forceinline__ void load16_lds(const u16* g, u16* l) {
  __builtin_amdgcn_global_load_lds(
      (const __attribute__((address_space(1))) unsigned int*)(const void*)g,
      (__attribute__((address_space(3))) unsigned int*)(void*)l, 16, 0, 0);
}

#define MFMA_(a, b, c) __builtin_amdgcn_mfma_f32_16x16x32_bf16(a, b, c, 0, 0, 0)

// ------------------------- 3 weight matrices -> Wk, Wvq=concat(Wv,Wq) ------
__global__ __launch_bounds__(256) void k_convw(const float* __restrict__ kw,
                                               const float* __restrict__ vw,
                                               const float* __restrict__ qw,
                                               u16* __restrict__ Wk,
                                               u16* __restrict__ Wvq) {
  const int w = blockIdx.x >> 7;
  const int b = blockIdx.x & 127;
  const float* src = (w == 0) ? kw : (w == 1) ? vw : qw;
  u16* dst = (w == 0) ? Wk : (Wvq + (size_t)(w - 1) * DDIM * DDIM);
  for (int i = b * 256 + threadIdx.x; i < DDIM * DDIM / 8; i += 128 * 256) {
    const float4* p = (const float4*)(src + (size_t)i * 8);
    float4 f0 = p[0], f1 = p[1];
    u16x8 o;
    o[0] = f2bf(f0.x); o[1] = f2bf(f0.y); o[2] = f2bf(f0.z); o[3] = f2bf(f0.w);
    o[4] = f2bf(f1.x); o[5] = f2bf(f1.y); o[6] = f2bf(f1.z); o[7] = f2bf(f1.w);
    *(u16x8*)(dst + (size_t)i * 8) = o;
  }
}

// ------------------------- r6 128^2 GEMM (fp32-A path), K-chain only -------
template<int AFP32>
__global__ __launch_bounds__(256) void k_gemm(const float* __restrict__ Af,
                                              const u16* __restrict__ Ab,
                                              const u16* __restrict__ B,
                                              u16* __restrict__ C,
                                              int lnn, int ldc) {
  __shared__ __align__(16) u16 As[128 * 32];
  __shared__ __align__(16) u16 Bs[128 * 32];
  const int tid  = threadIdx.x;
  const int lane = tid & 63;
  const int cpx = gridDim.x >> 3;                       // nwg % 8 == 0
  const int v   = (blockIdx.x & 7) * cpx + (blockIdx.x >> 3);
  const int m0 = (v >> lnn) * 128;
  const int n0 = (v & ((1 << lnn) - 1)) * 128;
  const int wid = tid >> 6;
  const int wr = (wid >> 1) * 64;
  const int wc = (wid & 1) * 64;

  const int rA = tid >> 2;                              // 0..63
  const int slotl = tid & 3;                            // logical 8-elem slot
  const int swz = (rA >> 1) & 3;
  const int cA = ((slotl ^ swz) << 3);                  // swizzled source slot
  const u16* Bp0 = B + (size_t)(n0 + rA) * DDIM + cA;
  const u16* Bp1 = Bp0 + (size_t)64 * DDIM;
  const u16* Ap0 = nullptr; const u16* Ap1 = nullptr;
  const float* Fp0 = nullptr; const float* Fp1 = nullptr;
  bool av0 = false, av1 = false;
  if (AFP32) {
    av0 = (m0 + rA) < NROWS;
    av1 = (m0 + rA + 64) < NROWS;
    Fp0 = Af + (size_t)(m0 + rA) * DDIM + slotl * 8;
    Fp1 = Fp0 + (size_t)64 * DDIM;
  } else {
    Ap0 = Ab + (size_t)(m0 + rA) * DDIM + cA;
    Ap1 = Ap0 + (size_t)64 * DDIM;
  }
  const int wbase = wid * 64;
  u16* AsD0 = &As[(wbase)       * 8];
  u16* AsD1 = &As[(wbase + 256) * 8];
  u16* BsD0 = &Bs[(wbase)       * 8];
  u16* BsD1 = &Bs[(wbase + 256) * 8];
  u16* AsW0 = &As[rA * 32 + cA];
  u16* AsW1 = &As[(rA + 64) * 32 + cA];

  f32x4 acc[4][4] = {};
  const int fr = lane & 15;
  const int T  = lane >> 4;

  for (int k0 = 0; k0 < DDIM; k0 += 32) {
    float4 fa0, fb0, fa1, fb1;
    if (AFP32) {
      if (av0) { fa0 = *(const float4*)(Fp0 + k0); fb0 = *(const float4*)(Fp0 + k0 + 4); }
      if (av1) { fa1 = *(const float4*)(Fp1 + k0); fb1 = *(const float4*)(Fp1 + k0 + 4); }
    }
    __syncthreads();
    if (AFP32) {
      u16x8 o0 = {0,0,0,0,0,0,0,0}, o1 = {0,0,0,0,0,0,0,0};
      if (av0) {
        o0[0]=f2bf(fa0.x); o0[1]=f2bf(fa0.y); o0[2]=f2bf(fa0.z); o0[3]=f2bf(fa0.w);
        o0[4]=f2bf(fb0.x); o0[5]=f2bf(fb0.y); o0[6]=f2bf(fb0.z); o0[7]=f2bf(fb0.w);
      }
      if (av1) {
        o1[0]=f2bf(fa1.x); o1[1]=f2bf(fa1.y); o1[2]=f2bf(fa1.z); o1[3]=f2bf(fa1.w);
        o1[4]=f2bf(fb1.x); o1[5]=f2bf(fb1.y); o1[6]=f2bf(fb1.z); o1[7]=f2bf(fb1.w);
      }
      *(u16x8*)AsW0 = o0;
      *(u16x8*)AsW1 = o1;
    } else {
      load16_lds(Ap0 + k0, AsD0);
      load16_lds(Ap1 + k0, AsD1);
    }
    load16_lds(Bp0 + k0, BsD0);
    load16_lds(Bp1 + k0, BsD1);
    __syncthreads();
    bf16x8 a[4], b[4];
#pragma unroll
    for (int i = 0; i < 4; ++i) {
      const int R = wr + i * 16 + fr;
      a[i] = *(const bf16x8*)&As[R * 32 + ((T ^ ((R >> 1) & 3)) << 3)];
    }
#pragma unroll
    for (int j = 0; j < 4; ++j) {
      const int R = wc + j * 16 + fr;
      b[j] = *(const bf16x8*)&Bs[R * 32 + ((T ^ ((R >> 1) & 3)) << 3)];
    }
#pragma unroll
    for (int i = 0; i < 4; ++i)
#pragma unroll
      for (int j = 0; j < 4; ++j)
        acc[i][j] = MFMA_(a[i], b[j], acc[i][j]);
  }

  const int orow = (lane >> 4) * 4;
  const int ocol = lane & 15;
#pragma unroll
  for (int i = 0; i < 4; ++i)
#pragma unroll
    for (int j = 0; j < 4; ++j) {
      const size_t base = (size_t)(m0 + wr + i * 16 + orow) * ldc + (n0 + wc + j * 16 + ocol);
#pragma unroll
      for (int r = 0; r < 4; ++r)
        C[base + (size_t)r * ldc] = f2bf(acc[i][j][r]);
    }
}

// ------------------------- 256^2 phased GEMM (VQ: bf16 A, bf16 B) ----------
// C[m,n] = sum_k A[m,k]*B[n,k].  M=50176 (196 tiles) x N=2048 (8 tiles).
// 8 waves: wr=wid>>2 (A-half), wc=wid&3 (64-col group, B-half wc>>1).
// LDS: A,B x 2 bufs x 2 halves x (128x64 bf16) = 128 KiB (dynamic).
// Per K-tile: 4 phases {stage | ds_read | setprio+16 MFMA} + raw s_barrier;
// waits: lgkmcnt(0)+vmcnt(0) only at the iteration-final barrier.
__global__ __launch_bounds__(512, 2) void k_gemm256(const u16* __restrict__ A,
                                                    const u16* __restrict__ Bw,
                                                    u16* __restrict__ C) {
  extern __shared__ __align__(16) u16 smem[];
  u16* Abase = smem;                 // [2][2][8192]
  u16* Bbase = smem + 32768;         // [2][2][8192]
  const int tid  = threadIdx.x;
  const int lane = tid & 63;
  const int wid  = tid >> 6;
  const int wr = wid >> 2;           // 0..1  : A half (128 rows)
  const int wc = wid & 3;            // 0..3  : 64-col group
  const int bh = wc >> 1;            // B half this wave reads
  const int bl = (wc & 1) * 64;      // local n-row base within B half
  const int fr = lane & 15;
  const int T  = lane >> 4;
  const int v  = (blockIdx.x & 7) * 196 + (blockIdx.x >> 3);   // 1568 blocks
  const int m0 = (v >> 3) * 256;
  const int n0 = (v & 7) * 256;

  f32x4 acc[8][4] = {};

#define STAGE_A(KT, BB) do {                                                   \
    _Pragma("unroll") for (int h_ = 0; h_ < 2; ++h_)                           \
      _Pragma("unroll") for (int l_ = 0; l_ < 2; ++l_) {                       \
        const int s_ = l_ * 512 + tid;                                         \
        const int r_ = s_ >> 3;                                                \
        const int c_ = (s_ & 7) ^ (r_ & 7);                                    \
        load16_lds(A + (size_t)(m0 + h_ * 128 + r_) * DDIM + (KT) * 64 + c_ * 8, \
                   Abase + ((BB) * 2 + h_) * 8192 + s_ * 8);                   \
      } } while (0)

#define STAGE_B(KT, BB) do {                                                   \
    _Pragma("unroll") for (int h_ = 0; h_ < 2; ++h_)                           \
      _Pragma("unroll") for (int l_ = 0; l_ < 2; ++l_) {                       \
        const int s_ = l_ * 512 + tid;                                         \
        const int r_ = s_ >> 3;                                                \
        const int c_ = (s_ & 7) ^ (r_ & 7);                                    \
        load16_lds(Bw + (size_t)(n0 + h_ * 128 + r_) * DDIM + (KT) * 64 + c_ * 8, \
                   Bbase + ((BB) * 2 + h_) * 8192 + s_ * 8);                   \
      } } while (0)

#define PHASE_A(p) do {                                                        \
    bf16x8 afr[4];                                                             \
    _Pragma("unroll") for (int ks = 0; ks < 2; ++ks)                           \
      _Pragma("unroll") for (int ii = 0; ii < 2; ++ii) {                       \
        const int R = ((p) * 2 + ii) * 16 + fr;                                \
        afr[ks * 2 + ii] = *(const bf16x8*)&Ap[R * 64 + (((ks * 4 + T) ^ (R & 7)) << 3)]; \
      }                                                                        \
    __builtin_amdgcn_s_setprio(1);                                             \
    _Pragma("unroll") for (int ks = 0; ks < 2; ++ks)                           \
      _Pragma("unroll") for (int ii = 0; ii < 2; ++ii)                         \
        _Pragma("unroll") for (int j = 0; j < 4; ++j)                          \
          acc[(p) * 2 + ii][j] = MFMA_(afr[ks * 2 + ii], bfr[ks * 4 + j],      \
                                       acc[(p) * 2 + ii][j]);                  \
    __builtin_amdgcn_s_setprio(0);                                             \
  } while (0)

#define BARP() asm volatile("s_barrier" ::: "memory")

  // prologue: stage kt=0 into buf 0, drain, barrier
  STAGE_A(0, 0);
  STAGE_B(0, 0);
  asm volatile("s_waitcnt vmcnt(0)\n\ts_barrier" ::: "memory");

  for (int kt = 0; kt < 16; ++kt) {
    const int b = kt & 1;
    const u16* Ap = Abase + (b * 2 + wr) * 8192;
    const u16* Bp = Bbase + (b * 2 + bh) * 8192;
    const bool st = kt < 15;
    bf16x8 bfr[8];
    // PH1: stage A(kt+1) into dead buf; read all B-frags + A row-pair 0
    if (st) STAGE_A(kt + 1, b ^ 1);
#pragma unroll
    for (int ks = 0; ks < 2; ++ks)
#pragma unroll
      for (int j = 0; j < 4; ++j) {
        const int R = bl + j * 16 + fr;
        bfr[ks * 4 + j] = *(const bf16x8*)&Bp[R * 64 + (((ks * 4 + T) ^ (R & 7)) << 3)];
      }
    PHASE_A(0);
    BARP();
    // PH2: stage B(kt+1); row-pair 1
    if (st) STAGE_B(kt + 1, b ^ 1);
    PHASE_A(1);
    BARP();
    // PH3
    PHASE_A(2);
    BARP();
    // PH4: iteration-final: all ds_reads drained, incoming tile landed
    PHASE_A(3);
    if (st)
      asm volatile("s_waitcnt vmcnt(0) lgkmcnt(0)\n\ts_barrier" ::: "memory");
  }
#undef STAGE_A
#undef STAGE_B
#undef PHASE_A
#undef BARP

  // epilogue: C write (ldc = 2048)
#pragma unroll
  for (int i = 0; i < 8; ++i)
#pragma unroll
    for (int j = 0; j < 4; ++j) {
      const size_t base = (size_t)(m0 + wr * 128 + i * 16 + T * 4) * 2048
                        + (n0 + wc * 64 + j * 16 + fr);
#pragma unroll
      for (int r = 0; r < 4; ++r)
        C[base + (size_t)r * 2048] = f2bf(acc[i][j][r]);
    }
}

// ------------------------- bias + LN + GELU for K (zero-pads rows) ---------
__global__ __launch_bounds__(256) void k_ln_k(const u16* __restrict__ h,
                                              const float* __restrict__ bias,
                                              const float* __restrict__ g,
                                              const float* __restrict__ beta,
                                              u16* __restrict__ out) {
  const int lane = threadIdx.x & 63;
  const int row = blockIdx.x * 4 + (threadIdx.x >> 6);
  const int c0 = lane * 8;
  u16x8* op0 = (u16x8*)(out + (size_t)row * DDIM + c0);
  u16x8* op1 = (u16x8*)(out + (size_t)row * DDIM + 512 + c0);
  if (row >= NROWS) {
    u16x8 z = {0, 0, 0, 0, 0, 0, 0, 0};
    *op0 = z; *op1 = z;
    return;
  }
  u16x8 h0 = *(const u16x8*)(h + (size_t)row * DDIM + c0);
  u16x8 h1 = *(const u16x8*)(h + (size_t)row * DDIM + 512 + c0);
  float4 a0 = *(const float4*)(bias + c0), a1 = *(const float4*)(bias + c0 + 4);
  float4 a2 = *(const float4*)(bias + 512 + c0), a3 = *(const float4*)(bias + 512 + c0 + 4);
  const float ba[8] = {a0.x, a0.y, a0.z, a0.w, a1.x, a1.y, a1.z, a1.w};
  const float bb[8] = {a2.x, a2.y, a2.z, a2.w, a3.x, a3.y, a3.z, a3.w};
  float v0[8], v1[8];
  float s1 = 0.f, s2 = 0.f;
#pragma unroll
  for (int e = 0; e < 8; ++e) {
    v0[e] = bf2f(h0[e]) + ba[e];
    v1[e] = bf2f(h1[e]) + bb[e];
    s1 += v0[e] + v1[e];
    s2 += v0[e] * v0[e] + v1[e] * v1[e];
  }
#pragma unroll
  for (int m = 1; m < 64; m <<= 1) {
    s1 += __shfl_xor(s1, m, 64);
    s2 += __shfl_xor(s2, m, 64);
  }
  const float mu = s1 * (1.0f / 1024.0f);
  const float var = s2 * (1.0f / 1024.0f) - mu * mu;
  const float rs = rsqrtf(var + 1e-5f);
  float4 g0 = *(const float4*)(g + c0), g1 = *(const float4*)(g + c0 + 4);
  float4 g2 = *(const float4*)(g + 512 + c0), g3 = *(const float4*)(g + 512 + c0 + 4);
  float4 t0 = *(const float4*)(beta + c0), t1 = *(const float4*)(beta + c0 + 4);
  float4 t2 = *(const float4*)(beta + 512 + c0), t3 = *(const float4*)(beta + 512 + c0 + 4);
  const float ga[8] = {g0.x, g0.y, g0.z, g0.w, g1.x, g1.y, g1.z, g1.w};
  const float gb[8] = {g2.x, g2.y, g2.z, g2.w, g3.x, g3.y, g3.z, g3.w};
  const float ta[8] = {t0.x, t0.y, t0.z, t0.w, t1.x, t1.y, t1.z, t1.w};
  const float tb[8] = {t2.x, t2.y, t2.z, t2.w, t3.x, t3.y, t3.z, t3.w};
  u16x8 o0, o1;
#pragma unroll
  for (int e = 0; e < 8; ++e) {
    o0[e] = f2bf(gelu((v0[e] - mu) * rs * ga[e] + ta[e]));
    o1[e] = f2bf(gelu((v1[e] - mu) * rs * gb[e] + tb[e]));
  }
  *op0 = o0; *op1 = o1;
}

// ------------------------- q_max from HbVQ rows (fin of argmax inside) -----
__global__ __launch_bounds__(64) void k_qmax2(const float* __restrict__ argv,
                                              const int* __restrict__ argi,
                                              const u16* __restrict__ hvq,
                                              const float* __restrict__ qb,
                                              const float* __restrict__ qg,
                                              const float* __restrict__ qbeta,
                                              u16* __restrict__ qm) {
  const int j = blockIdx.x;
  const int lane = threadIdx.x;
  float bv = -3.4e38f; int bi = 0x7fffffff;
  for (int p = lane; p < 128; p += 64) {
    const float v = argv[p * NCLS + j];
    const int   i = argi[p * NCLS + j];
    if (v > bv || (v == bv && i < bi)) { bv = v; bi = i; }
  }
#pragma unroll
  for (int m = 1; m < 64; m <<= 1) {
    const float ov = __shfl_xor(bv, m, 64);
    const int   oi = __shfl_xor(bi, m, 64);
    if (ov > bv || (ov == bv && oi < bi)) { bv = ov; bi = oi; }
  }
  const int row = bi;
  const int c0 = lane * 8;
  const u16* hp = hvq + (size_t)row * 2048 + DDIM;      // Q-half
  u16x8 h0 = *(const u16x8*)(hp + c0);
  u16x8 h1 = *(const u16x8*)(hp + 512 + c0);
  float v0[8], v1[8];
  float s1 = 0.f, s2 = 0.f;
#pragma unroll
  for (int e = 0; e < 8; ++e) {
    v0[e] = bf2f(h0[e]) + qb[c0 + e];
    v1[e] = bf2f(h1[e]) + qb[512 + c0 + e];
    s1 += v0[e] + v1[e];
    s2 += v0[e] * v0[e] + v1[e] * v1[e];
  }
#pragma unroll
  for (int m = 1; m < 64; m <<= 1) {
    s1 += __shfl_xor(s1, m, 64);
    s2 += __shfl_xor(s2, m, 64);
  }
  const float mu = s1 * (1.0f / 1024.0f);
  const float var = s2 * (1.0f / 1024.0f) - mu * mu;
  const float rs = rsqrtf(var + 1e-5f);
  u16x8 o0, o1;
#pragma unroll
  for (int e = 0; e < 8; ++e) {
    o0[e] = f2bf(gelu((v0[e] - mu) * rs * qg[c0 + e] + qbeta[c0 + e]));
    o1[e] = f2bf(gelu((v1[e] - mu) * rs * qg[512 + c0 + e] + qbeta[512 + c0 + e]));
  }
  *(u16x8*)(qm + (size_t)j * DDIM + c0) = o0;
  *(u16x8*)(qm + (size_t)j * DDIM + 512 + c0) = o1;
}

// ------------------------- merged V/Q LN; Q-half emits logits only ---------
__global__ __launch_bounds__(256) void k_ln_vq(const u16* __restrict__ h,
                                               const float* __restrict__ v_b,
                                               const float* __restrict__ v_g,
                                               const float* __restrict__ v_beta,
                                               const float* __restrict__ q_b,
                                               const float* __restrict__ q_g,
                                               const float* __restrict__ q_beta,
                                               const u16* __restrict__ qm,
                                               u16* __restrict__ V,
                                               float* __restrict__ logits) {
  __shared__ __align__(16) u16 sqm[NCLS * DDIM];        // 14 KB
  const int tid = threadIdx.x;
  const int lane = tid & 63;
  const int half = (blockIdx.x >= MPD4) ? 1 : 0;
  const int rb = half ? (blockIdx.x - MPD4) : blockIdx.x;
  const int row = rb * 4 + (tid >> 6);
  if (half) {
    for (int i = tid; i < NCLS * DDIM / 8; i += 256)
      *(u16x8*)&sqm[i * 8] = *(const u16x8*)&qm[i * 8];
    __syncthreads();
  }
  if (row >= NROWS) return;                             // no sync after this
  const float* bias = half ? q_b : v_b;
  const float* gain = half ? q_g : v_g;
  const float* bet  = half ? q_beta : v_beta;
  const int c0 = lane * 8;
  const u16* hp = h + (size_t)row * 2048 + (size_t)half * DDIM;
  u16x8 h0 = *(const u16x8*)(hp + c0);
  u16x8 h1 = *(const u16x8*)(hp + 512 + c0);
  float4 a0 = *(const float4*)(bias + c0), a1 = *(const float4*)(bias + c0 + 4);
  float4 a2 = *(const float4*)(bias + 512 + c0), a3 = *(const float4*)(bias + 512 + c0 + 4);
  const float ba[8] = {a0.x, a0.y, a0.z, a0.w, a1.x, a1.y, a1.z, a1.w};
  const float bb[8] = {a2.x, a2.y, a2.z, a2.w, a3.x, a3.y, a3.z, a3.w};
  float v0[8], v1[8];
  float s1 = 0.f, s2 = 0.f;
#pragma unroll
  for (int e = 0; e < 8; ++e) {
    v0[e] = bf2f(h0[e]) + ba[e];
    v1[e] = bf2f(h1[e]) + bb[e];
    s1 += v0[e] + v1[e];
    s2 += v0[e] * v0[e] + v1[e] * v1[e];
  }
#pragma unroll
  for (int m = 1; m < 64; m <<= 1) {
    s1 += __shfl_xor(s1, m, 64);
    s2 += __shfl_xor(s2, m, 64);
  }
  const float mu = s1 * (1.0f / 1024.0f);
  const float var = s2 * (1.0f / 1024.0f) - mu * mu;
  const float rs = rsqrtf(var + 1e-5f);
  float4 g0 = *(const float4*)(gain + c0), g1 = *(const float4*)(gain + c0 + 4);
  float4 g2 = *(const float4*)(gain + 512 + c0), g3 = *(const float4*)(gain + 512 + c0 + 4);
  float4 t0 = *(const float4*)(bet + c0), t1 = *(const float4*)(bet + c0 + 4);
  float4 t2 = *(const float4*)(bet + 512 + c0), t3 = *(const float4*)(bet + 512 + c0 + 4);
  const float ga[8] = {g0.x, g0.y, g0.z, g0.w, g1.x, g1.y, g1.z, g1.w};
  const float gb[8] = {g2.x, g2.y, g2.z, g2.w, g3.x, g3.y, g3.z, g3.w};
  const float ta[8] = {t0.x, t0.y, t0.z, t0.w, t1.x, t1.y, t1.z, t1.w};
  const float tb[8] = {t2.x, t2.y, t2.z, t2.w, t3.x, t3.y, t3.z, t3.w};
  float y0[8], y1[8];
#pragma unroll
  for (int e = 0; e < 8; ++e) {
    y0[e] = gelu((v0[e] - mu) * rs * ga[e] + ta[e]);
    y1[e] = gelu((v1[e] - mu) * rs * gb[e] + tb[e]);
  }
  if (half == 0) {
    u16x8 o0, o1;
#pragma unroll
    for (int e = 0; e < 8; ++e) { o0[e] = f2bf(y0[e]); o1[e] = f2bf(y1[e]); }
    *(u16x8*)(V + (size_t)row * DDIM + c0) = o0;
    *(u16x8*)(V + (size_t)row * DDIM + 512 + c0) = o1;
  } else {
#pragma unroll
    for (int j = 0; j < NCLS; ++j) {
      u16x8 m0 = *(const u16x8*)&sqm[j * DDIM + c0];
      u16x8 m1 = *(const u16x8*)&sqm[j * DDIM + 512 + c0];
      float p = 0.f;
#pragma unroll
      for (int e = 0; e < 8; ++e) p += y0[e] * bf2f(m0[e]) + y1[e] * bf2f(m1[e]);
#pragma unroll
      for (int m = 1; m < 64; m <<= 1) p += __shfl_xor(p, m, 64);
      if (lane == 0) logits[(size_t)row * NCLS + j] = p * 0.03125f;
    }
  }
}

// ------------------------- argmax partials (first-index) -------------------
__global__ __launch_bounds__(256) void k_arg1(const float* __restrict__ c,
                                              float* __restrict__ pv,
                                              int* __restrict__ pi) {
  __shared__ float sv[256 * NCLS];
  __shared__ int   si[256 * NCLS];
  const int t = threadIdx.x;
  float bv[NCLS]; int bi[NCLS];
#pragma unroll
  for (int j = 0; j < NCLS; ++j) { bv[j] = -3.4e38f; bi[j] = 0x7fffffff; }
  for (int n = blockIdx.x * 256 + t; n < NROWS; n += 128 * 256) {
#pragma unroll
    for (int j = 0; j < NCLS; ++j) {
      const float v = c[(size_t)n * NCLS + j];
      if (v > bv[j]) { bv[j] = v; bi[j] = n; }
    }
  }
#pragma unroll
  for (int j = 0; j < NCLS; ++j) { sv[t * NCLS + j] = bv[j]; si[t * NCLS + j] = bi[j]; }
  __syncthreads();
  for (int s = 128; s > 0; s >>= 1) {
    if (t < s) {
#pragma unroll
      for (int j = 0; j < NCLS; ++j) {
        const float v2 = sv[(t + s) * NCLS + j]; const int i2 = si[(t + s) * NCLS + j];
        const float v1 = sv[t * NCLS + j];       const int i1 = si[t * NCLS + j];
        if (v2 > v1 || (v2 == v1 && i2 < i1)) { sv[t * NCLS + j] = v2; si[t * NCLS + j] = i2; }
      }
    }
    __syncthreads();
  }
  if (t < NCLS) { pv[blockIdx.x * NCLS + t] = sv[t]; pi[blockIdx.x * NCLS + t] = si[t]; }
}

// ------------------------- one-pass softmax partials per block -------------
__global__ __launch_bounds__(256) void k_softpart(const float* __restrict__ logits,
                                                  float* __restrict__ Pm,
                                                  float* __restrict__ Ps) {
  __shared__ float sm[256 * NCLS];
  const int t = threadIdx.x;
  float m[NCLS];
#pragma unroll
  for (int j = 0; j < NCLS; ++j) m[j] = -3.4e38f;
  for (int n = blockIdx.x * 256 + t; n < NROWS; n += 128 * 256)
#pragma unroll
    for (int j = 0; j < NCLS; ++j) m[j] = fmaxf(m[j], logits[(size_t)n * NCLS + j]);
#pragma unroll
  for (int j = 0; j < NCLS; ++j) sm[t * NCLS + j] = m[j];
  __syncthreads();
  for (int s = 128; s > 0; s >>= 1) {
    if (t < s)
#pragma unroll
      for (int j = 0; j < NCLS; ++j)
        sm[t * NCLS + j] = fmaxf(sm[t * NCLS + j], sm[(t + s) * NCLS + j]);
    __syncthreads();
  }
  float mloc[NCLS];
#pragma unroll
  for (int j = 0; j < NCLS; ++j) mloc[j] = sm[j];
  __syncthreads();
  float s[NCLS];
#pragma unroll
  for (int j = 0; j < NCLS; ++j) s[j] = 0.f;
  for (int n = blockIdx.x * 256 + t; n < NROWS; n += 128 * 256)
#pragma unroll
    for (int j = 0; j < NCLS; ++j) s[j] += expf(logits[(size_t)n * NCLS + j] - mloc[j]);
#pragma unroll
  for (int j = 0; j < NCLS; ++j) sm[t * NCLS + j] = s[j];
  __syncthreads();
  for (int st = 128; st > 0; st >>= 1) {
    if (t < st)
#pragma unroll
      for (int j = 0; j < NCLS; ++j) sm[t * NCLS + j] += sm[(t + st) * NCLS + j];
    __syncthreads();
  }
  if (t < NCLS) { Pm[blockIdx.x * NCLS + t] = mloc[t]; Ps[blockIdx.x * NCLS + t] = sm[t]; }
}

// ------------------------- B-partials = A^T V, fused A-write + rescale-fin -
__global__ __launch_bounds__(256) void k_bpart(const float* __restrict__ logits,
                                               const float* __restrict__ Pm,
                                               const float* __restrict__ Ps,
                                               const u16* __restrict__ V,
                                               float* __restrict__ Aout,
                                               float* __restrict__ Pb) {
  __shared__ float sA[98 * NCLS];
  __shared__ float sM[NCLS], sR[NCLS];
  const int t = threadIdx.x;
  if (t < NCLS) {
    float M = -3.4e38f;
    for (int b = 0; b < 128; ++b) M = fmaxf(M, Pm[b * NCLS + t]);
    float S = 0.f;
    for (int b = 0; b < 128; ++b) S += Ps[b * NCLS + t] * expf(Pm[b * NCLS + t] - M);
    sM[t] = M; sR[t] = 1.0f / S;
  }
  __syncthreads();
  const int n0 = blockIdx.x * 98;
  int cnt = NROWS - n0;
  cnt = cnt < 0 ? 0 : (cnt > 98 ? 98 : cnt);
  for (int idx = t; idx < cnt * NCLS; idx += 256) {
    const int j = idx % NCLS;
    const float a = expf(logits[(size_t)n0 * NCLS + idx] - sM[j]) * sR[j];
    sA[idx] = a;
    Aout[(size_t)n0 * NCLS + idx] = a;
  }
  __syncthreads();
  float acc[NCLS][4] = {};
  for (int r = 0; r < cnt; ++r) {
    u16x4 vv = *(const u16x4*)&V[(size_t)(n0 + r) * DDIM + t * 4];
    const float f0 = bf2f(vv[0]), f1 = bf2f(vv[1]), f2 = bf2f(vv[2]), f3 = bf2f(vv[3]);
#pragma unroll
    for (int j = 0; j < NCLS; ++j) {
      const float a = sA[r * NCLS + j];
      acc[j][0] += a * f0; acc[j][1] += a * f1; acc[j][2] += a * f2; acc[j][3] += a * f3;
    }
  }
#pragma unroll
  for (int j = 0; j < NCLS; ++j) {
    f32x4 o = {acc[j][0], acc[j][1], acc[j][2], acc[j][3]};
    *(f32x4*)&Pb[((size_t)blockIdx.x * NCLS + j) * DDIM + t * 4] = o;
  }
}

__global__ void k_bred(const float* __restrict__ Pb, float* __restrict__ Bout) {
  const int idx = blockIdx.x * 256 + threadIdx.x;
  if (idx >= NCLS * DDIM) return;
  float s = 0.f;
  for (int p = 0; p < 512; ++p) s += Pb[(size_t)p * NCLS * DDIM + idx];
  Bout[idx] = s;
}

// ------------------------- C[o] = <B, head_w[o]> + head_b[o] ---------------
__global__ __launch_bounds__(256) void k_head(const float* __restrict__ Bmat,
                                              const float* __restrict__ hw,
                                              const float* __restrict__ hb,
                                              float* __restrict__ Cout) {
  const int o = blockIdx.x, t = threadIdx.x;
  float p = 0.f;
  for (int idx = t; idx < NCLS * DDIM; idx += 256)
    p += Bmat[idx] * hw[(size_t)o * NCLS * DDIM + idx];
#pragma unroll
  for (int m = 1; m < 64; m <<= 1) p += __shfl_xor(p, m, 64);
  __shared__ float w[4];
  if ((t & 63) == 0) w[t >> 6] = p;
  __syncthreads();
  if (t == 0) Cout[o] = w[0] + w[1] + w[2] + w[3] + hb[o];
}

// ---------------------------------------------------------------------------
extern "C" void kernel_launch(void* const* d_in, const int* in_sizes, int n_in,
                              void* d_out, int out_size, void* d_ws, size_t ws_size,
                              hipStream_t stream) {
  const float* features   = (const float*)d_in[0];
  const float* c_in       = (const float*)d_in[1];
  const float* key_w      = (const float*)d_in[2];
  const float* key_b      = (const float*)d_in[3];
  const float* key_g      = (const float*)d_in[4];
  const float* key_beta   = (const float*)d_in[5];
  const float* query_w    = (const float*)d_in[6];
  const float* query_b    = (const float*)d_in[7];
  const float* query_g    = (const float*)d_in[8];
  const float* query_beta = (const float*)d_in[9];
  const float* value_w    = (const float*)d_in[10];
  const float* value_b    = (const float*)d_in[11];
  const float* value_g    = (const float*)d_in[12];
  const float* value_beta = (const float*)d_in[13];
  const float* head_w     = (const float*)d_in[14];
  const float* head_b     = (const float*)d_in[15];

  char* ws = (char*)d_ws;
  const size_t SZB = (size_t)MP * DDIM * 2;             // 102,760,448 B
  u16* HbK  = (u16*)ws;                                 // [MP,1024]
  u16* Kb   = (u16*)(ws + SZB);                         // [MP,1024]
  u16* HbVQ = (u16*)(ws + 2 * SZB);                     // [MP,2048]
  u16* Vb   = Kb;                                       // reuse after VQ-GEMM
  size_t off = 4 * SZB;
  u16* Wk  = (u16*)(ws + off); off += (size_t)DDIM * DDIM * 2;
  u16* Wvq = (u16*)(ws + off); off += (size_t)2 * DDIM * DDIM * 2;
  float* logits = (float*)(ws + off); off += ((size_t)NROWS * NCLS * 4 + 255) & ~(size_t)255;
  float* Pb  = (float*)(ws + off); off += (size_t)512 * NCLS * DDIM * 4;
  u16* qm    = (u16*)(ws + off); off += ((size_t)NCLS * DDIM * 2 + 255) & ~(size_t)255;
  float* Pmax = (float*)(ws + off); off += ((size_t)128 * NCLS * 4 + 255) & ~(size_t)255;
  float* Psum = (float*)(ws + off); off += ((size_t)128 * NCLS * 4 + 255) & ~(size_t)255;
  float* argv = (float*)(ws + off); off += ((size_t)128 * NCLS * 4 + 255) & ~(size_t)255;
  int*   argi = (int*)  (ws + off); off += ((size_t)128 * NCLS * 4 + 255) & ~(size_t)255;

  float* Cout = (float*)d_out;                          // [7]
  float* Aout = Cout + NCLS;                            // [50000,7]
  float* Bout = Aout + (size_t)NROWS * NCLS;            // [7,1024]

  // argmax partials + weight converts
  k_arg1<<<128, 256, 0, stream>>>(c_in, argv, argi);
  k_convw<<<384, 256, 0, stream>>>(key_w, value_w, query_w, Wk, Wvq);

  // K chain: fp32-A GEMM (no convert pass), then LN (zero-pads to MP)
  k_gemm<1><<<3136, 256, 0, stream>>>(features, nullptr, Wk, HbK, 3, 1024);
  k_ln_k<<<MPD4, 256, 0, stream>>>(HbK, key_b, key_g, key_beta, Kb);

  // merged V|Q GEMM: 256^2 phased kernel (196 x 8 tiles, 128 KiB dynamic LDS)
  k_gemm256<<<1568, 512, 131072, stream>>>(Kb, Wvq, HbVQ);
  k_qmax2<<<NCLS, 64, 0, stream>>>(argv, argi, HbVQ, query_b, query_g, query_beta, qm);
  k_ln_vq<<<2 * MPD4, 256, 0, stream>>>(HbVQ, value_b, value_g, value_beta,
                                        query_b, query_g, query_beta, qm, Vb, logits);

  // softmax over axis 0: one-pass partials, rescale-fin in consumer
  k_softpart<<<128, 256, 0, stream>>>(logits, Pmax, Psum);

  // B = A^T V (A materialized on the fly), head contraction
  k_bpart<<<512, 256, 0, stream>>>(logits, Pmax, Psum, Vb, Aout, Pb);
  k_bred<<<28, 256, 0, stream>>>(Pb, Bout);
  k_head<<<NCLS, 256, 0, stream>>>(Bout, head_w, head_b, Cout);
}

// Round 9
// 678.101 us; speedup vs baseline: 1.6690x; 1.0714x over previous
//
#include <hip/hip_runtime.h>

// ---------------------------------------------------------------------------
// AttDual round 8: both GEMMs through the 256x256/BK=64 phased kernel (8
// waves, raw-barrier phases, setprio, conflict-free swizzle). fp32 features
// go through a streaming convert (HBM-BW) instead of fp32-A reg staging.
// HbVQ aliases the dead Xb|HbK region. Tail identical to r7.
// ---------------------------------------------------------------------------

typedef unsigned short u16;
typedef __attribute__((ext_vector_type(8))) short          bf16x8;
typedef __attribute__((ext_vector_type(8))) unsigned short u16x8;
typedef __attribute__((ext_vector_type(4))) unsigned short u16x4;
typedef __attribute__((ext_vector_type(4))) float          f32x4;

#define DDIM  1024
#define NROWS 50000
#define MP    50176      // 196 * 256 padded rows (zeros)
#define NCLS  7
#define MPD4  12544      // MP/4

__device__ __forceinline__ u16 f2bf(float f) {          // RNE fp32 -> bf16
  unsigned u = __float_as_uint(f);
  u = (u + 0x7FFFu + ((u >> 16) & 1u)) >> 16;
  return (u16)u;
}
__device__ __forceinline__ float bf2f(u16 h) {
  return __uint_as_float(((unsigned)h) << 16);
}
__device__ __forceinline__ float gelu(float x) {
  return 0.5f * x * (1.0f + erff(x * 0.70710678118654752f));
}

__device__ __forceinline__ void load16_lds(const u16* g, u16* l) {
  __builtin_amdgcn_global_load_lds(
      (const __attribute__((address_space(1))) unsigned int*)(const void*)g,
      (__attribute__((address_space(3))) unsigned int*)(void*)l, 16, 0, 0);
}

#define MFMA_(a, b, c) __builtin_amdgcn_mfma_f32_16x16x32_bf16(a, b, c, 0, 0, 0)

// ------------------------- fp32 -> bf16 convert (features, +row zero-pad) --
__global__ __launch_bounds__(256) void k_convert(const float* __restrict__ src,
                                                 u16* __restrict__ dst,
                                                 int rows_total, int rows_valid) {
  const size_t total = (size_t)rows_total * DDIM / 8;
  const size_t stride = (size_t)gridDim.x * blockDim.x;
  for (size_t i = (size_t)blockIdx.x * blockDim.x + threadIdx.x; i < total; i += stride) {
    const size_t e = i * 8;
    const int row = (int)(e >> 10);
    u16x8 o = {0, 0, 0, 0, 0, 0, 0, 0};
    if (row < rows_valid) {
      const float4* p = (const float4*)(src + e);
      float4 f0 = p[0], f1 = p[1];
      o[0] = f2bf(f0.x); o[1] = f2bf(f0.y); o[2] = f2bf(f0.z); o[3] = f2bf(f0.w);
      o[4] = f2bf(f1.x); o[5] = f2bf(f1.y); o[6] = f2bf(f1.z); o[7] = f2bf(f1.w);
    }
    *(u16x8*)(dst + e) = o;
  }
}

// ------------------------- 3 weight matrices -> Wk, Wvq=concat(Wv,Wq) ------
__global__ __launch_bounds__(256) void k_convw(const float* __restrict__ kw,
                                               const float* __restrict__ vw,
                                               const float* __restrict__ qw,
                                               u16* __restrict__ Wk,
                                               u16* __restrict__ Wvq) {
  const int w = blockIdx.x >> 7;
  const int b = blockIdx.x & 127;
  const float* src = (w == 0) ? kw : (w == 1) ? vw : qw;
  u16* dst = (w == 0) ? Wk : (Wvq + (size_t)(w - 1) * DDIM * DDIM);
  for (int i = b * 256 + threadIdx.x; i < DDIM * DDIM / 8; i += 128 * 256) {
    const float4* p = (const float4*)(src + (size_t)i * 8);
    float4 f0 = p[0], f1 = p[1];
    u16x8 o;
    o[0] = f2bf(f0.x); o[1] = f2bf(f0.y); o[2] = f2bf(f0.z); o[3] = f2bf(f0.w);
    o[4] = f2bf(f1.x); o[5] = f2bf(f1.y); o[6] = f2bf(f1.z); o[7] = f2bf(f1.w);
    *(u16x8*)(dst + (size_t)i * 8) = o;
  }
}

// ------------------------- 256^2 phased GEMM (bf16 A, bf16 B^T layout) -----
// C[m,n] = sum_k A[m,k]*B[n,k].  M = 196 tiles; N-tiles = 1<<lnn; ldc given.
// 8 waves: wr=wid>>2 (A-half), wc=wid&3 (64-col group, B-half wc>>1).
// LDS: A,B x 2 bufs x 2 halves x (128x64 bf16) = 128 KiB (dynamic).
// Per K-tile: 4 phases {stage | ds_read | setprio+16 MFMA} + raw s_barrier;
// waits: lgkmcnt(0)+vmcnt(0) only at the iteration-final barrier.
__global__ __launch_bounds__(512, 2) void k_gemm256(const u16* __restrict__ A,
                                                    const u16* __restrict__ Bw,
                                                    u16* __restrict__ C,
                                                    int lnn, int ldc) {
  extern __shared__ __align__(16) u16 smem[];
  u16* Abase = smem;                 // [2][2][8192]
  u16* Bbase = smem + 32768;         // [2][2][8192]
  const int tid  = threadIdx.x;
  const int lane = tid & 63;
  const int wid  = tid >> 6;
  const int wr = wid >> 2;           // 0..1  : A half (128 rows)
  const int wc = wid & 3;            // 0..3  : 64-col group
  const int bh = wc >> 1;            // B half this wave reads
  const int bl = (wc & 1) * 64;      // local n-row base within B half
  const int fr = lane & 15;
  const int T  = lane >> 4;
  const int cpx = gridDim.x >> 3;                              // nwg % 8 == 0
  const int v  = (blockIdx.x & 7) * cpx + (blockIdx.x >> 3);
  const int m0 = (v >> lnn) * 256;
  const int n0 = (v & ((1 << lnn) - 1)) * 256;

  f32x4 acc[8][4] = {};

#define STAGE_A(KT, BB) do {                                                   \
    _Pragma("unroll") for (int h_ = 0; h_ < 2; ++h_)                           \
      _Pragma("unroll") for (int l_ = 0; l_ < 2; ++l_) {                       \
        const int s_ = l_ * 512 + tid;                                         \
        const int r_ = s_ >> 3;                                                \
        const int c_ = (s_ & 7) ^ (r_ & 7);                                    \
        load16_lds(A + (size_t)(m0 + h_ * 128 + r_) * DDIM + (KT) * 64 + c_ * 8, \
                   Abase + ((BB) * 2 + h_) * 8192 + s_ * 8);                   \
      } } while (0)

#define STAGE_B(KT, BB) do {                                                   \
    _Pragma("unroll") for (int h_ = 0; h_ < 2; ++h_)                           \
      _Pragma("unroll") for (int l_ = 0; l_ < 2; ++l_) {                       \
        const int s_ = l_ * 512 + tid;                                         \
        const int r_ = s_ >> 3;                                                \
        const int c_ = (s_ & 7) ^ (r_ & 7);                                    \
        load16_lds(Bw + (size_t)(n0 + h_ * 128 + r_) * DDIM + (KT) * 64 + c_ * 8, \
                   Bbase + ((BB) * 2 + h_) * 8192 + s_ * 8);                   \
      } } while (0)

#define PHASE_A(p) do {                                                        \
    bf16x8 afr[4];                                                             \
    _Pragma("unroll") for (int ks = 0; ks < 2; ++ks)                           \
      _Pragma("unroll") for (int ii = 0; ii < 2; ++ii) {                       \
        const int R = ((p) * 2 + ii) * 16 + fr;                                \
        afr[ks * 2 + ii] = *(const bf16x8*)&Ap[R * 64 + (((ks * 4 + T) ^ (R & 7)) << 3)]; \
      }                                                                        \
    __builtin_amdgcn_s_setprio(1);                                             \
    _Pragma("unroll") for (int ks = 0; ks < 2; ++ks)                           \
      _Pragma("unroll") for (int ii = 0; ii < 2; ++ii)                         \
        _Pragma("unroll") for (int j = 0; j < 4; ++j)                          \
          acc[(p) * 2 + ii][j] = MFMA_(afr[ks * 2 + ii], bfr[ks * 4 + j],      \
                                       acc[(p) * 2 + ii][j]);                  \
    __builtin_amdgcn_s_setprio(0);                                             \
  } while (0)

#define BARP() asm volatile("s_barrier" ::: "memory")

  // prologue: stage kt=0 into buf 0, drain, barrier
  STAGE_A(0, 0);
  STAGE_B(0, 0);
  asm volatile("s_waitcnt vmcnt(0)\n\ts_barrier" ::: "memory");

  for (int kt = 0; kt < 16; ++kt) {
    const int b = kt & 1;
    const u16* Ap = Abase + (b * 2 + wr) * 8192;
    const u16* Bp = Bbase + (b * 2 + bh) * 8192;
    const bool st = kt < 15;
    bf16x8 bfr[8];
    // PH1: stage A(kt+1) into dead buf; read all B-frags + A row-pair 0
    if (st) STAGE_A(kt + 1, b ^ 1);
#pragma unroll
    for (int ks = 0; ks < 2; ++ks)
#pragma unroll
      for (int j = 0; j < 4; ++j) {
        const int R = bl + j * 16 + fr;
        bfr[ks * 4 + j] = *(const bf16x8*)&Bp[R * 64 + (((ks * 4 + T) ^ (R & 7)) << 3)];
      }
    PHASE_A(0);
    BARP();
    // PH2: stage B(kt+1); row-pair 1
    if (st) STAGE_B(kt + 1, b ^ 1);
    PHASE_A(1);
    BARP();
    // PH3
    PHASE_A(2);
    BARP();
    // PH4: iteration-final: all ds_reads drained, incoming tile landed
    PHASE_A(3);
    if (st)
      asm volatile("s_waitcnt vmcnt(0) lgkmcnt(0)\n\ts_barrier" ::: "memory");
  }
#undef STAGE_A
#undef STAGE_B
#undef PHASE_A
#undef BARP

  // epilogue: C write
#pragma unroll
  for (int i = 0; i < 8; ++i)
#pragma unroll
    for (int j = 0; j < 4; ++j) {
      const size_t base = (size_t)(m0 + wr * 128 + i * 16 + T * 4) * ldc
                        + (n0 + wc * 64 + j * 16 + fr);
#pragma unroll
      for (int r = 0; r < 4; ++r)
        C[base + (size_t)r * ldc] = f2bf(acc[i][j][r]);
    }
}

// ------------------------- bias + LN + GELU for K (zero-pads rows) ---------
__global__ __launch_bounds__(256) void k_ln_k(const u16* __restrict__ h,
                                              const float* __restrict__ bias,
                                              const float* __restrict__ g,
                                              const float* __restrict__ beta,
                                              u16* __restrict__ out) {
  const int lane = threadIdx.x & 63;
  const int row = blockIdx.x * 4 + (threadIdx.x >> 6);
  const int c0 = lane * 8;
  u16x8* op0 = (u16x8*)(out + (size_t)row * DDIM + c0);
  u16x8* op1 = (u16x8*)(out + (size_t)row * DDIM + 512 + c0);
  if (row >= NROWS) {
    u16x8 z = {0, 0, 0, 0, 0, 0, 0, 0};
    *op0 = z; *op1 = z;
    return;
  }
  u16x8 h0 = *(const u16x8*)(h + (size_t)row * DDIM + c0);
  u16x8 h1 = *(const u16x8*)(h + (size_t)row * DDIM + 512 + c0);
  float4 a0 = *(const float4*)(bias + c0), a1 = *(const float4*)(bias + c0 + 4);
  float4 a2 = *(const float4*)(bias + 512 + c0), a3 = *(const float4*)(bias + 512 + c0 + 4);
  const float ba[8] = {a0.x, a0.y, a0.z, a0.w, a1.x, a1.y, a1.z, a1.w};
  const float bb[8] = {a2.x, a2.y, a2.z, a2.w, a3.x, a3.y, a3.z, a3.w};
  float v0[8], v1[8];
  float s1 = 0.f, s2 = 0.f;
#pragma unroll
  for (int e = 0; e < 8; ++e) {
    v0[e] = bf2f(h0[e]) + ba[e];
    v1[e] = bf2f(h1[e]) + bb[e];
    s1 += v0[e] + v1[e];
    s2 += v0[e] * v0[e] + v1[e] * v1[e];
  }
#pragma unroll
  for (int m = 1; m < 64; m <<= 1) {
    s1 += __shfl_xor(s1, m, 64);
    s2 += __shfl_xor(s2, m, 64);
  }
  const float mu = s1 * (1.0f / 1024.0f);
  const float var = s2 * (1.0f / 1024.0f) - mu * mu;
  const float rs = rsqrtf(var + 1e-5f);
  float4 g0 = *(const float4*)(g + c0), g1 = *(const float4*)(g + c0 + 4);
  float4 g2 = *(const float4*)(g + 512 + c0), g3 = *(const float4*)(g + 512 + c0 + 4);
  float4 t0 = *(const float4*)(beta + c0), t1 = *(const float4*)(beta + c0 + 4);
  float4 t2 = *(const float4*)(beta + 512 + c0), t3 = *(const float4*)(beta + 512 + c0 + 4);
  const float ga[8] = {g0.x, g0.y, g0.z, g0.w, g1.x, g1.y, g1.z, g1.w};
  const float gb[8] = {g2.x, g2.y, g2.z, g2.w, g3.x, g3.y, g3.z, g3.w};
  const float ta[8] = {t0.x, t0.y, t0.z, t0.w, t1.x, t1.y, t1.z, t1.w};
  const float tb[8] = {t2.x, t2.y, t2.z, t2.w, t3.x, t3.y, t3.z, t3.w};
  u16x8 o0, o1;
#pragma unroll
  for (int e = 0; e < 8; ++e) {
    o0[e] = f2bf(gelu((v0[e] - mu) * rs * ga[e] + ta[e]));
    o1[e] = f2bf(gelu((v1[e] - mu) * rs * gb[e] + tb[e]));
  }
  *op0 = o0; *op1 = o1;
}

// ------------------------- q_max from HbVQ rows (fin of argmax inside) -----
__global__ __launch_bounds__(64) void k_qmax2(const float* __restrict__ argv,
                                              const int* __restrict__ argi,
                                              const u16* __restrict__ hvq,
                                              const float* __restrict__ qb,
                                              const float* __restrict__ qg,
                                              const float* __restrict__ qbeta,
                                              u16* __restrict__ qm) {
  const int j = blockIdx.x;
  const int lane = threadIdx.x;
  float bv = -3.4e38f; int bi = 0x7fffffff;
  for (int p = lane; p < 128; p += 64) {
    const float v = argv[p * NCLS + j];
    const int   i = argi[p * NCLS + j];
    if (v > bv || (v == bv && i < bi)) { bv = v; bi = i; }
  }
#pragma unroll
  for (int m = 1; m < 64; m <<= 1) {
    const float ov = __shfl_xor(bv, m, 64);
    const int   oi = __shfl_xor(bi, m, 64);
    if (ov > bv || (ov == bv && oi < bi)) { bv = ov; bi = oi; }
  }
  const int row = bi;
  const int c0 = lane * 8;
  const u16* hp = hvq + (size_t)row * 2048 + DDIM;      // Q-half
  u16x8 h0 = *(const u16x8*)(hp + c0);
  u16x8 h1 = *(const u16x8*)(hp + 512 + c0);
  float v0[8], v1[8];
  float s1 = 0.f, s2 = 0.f;
#pragma unroll
  for (int e = 0; e < 8; ++e) {
    v0[e] = bf2f(h0[e]) + qb[c0 + e];
    v1[e] = bf2f(h1[e]) + qb[512 + c0 + e];
    s1 += v0[e] + v1[e];
    s2 += v0[e] * v0[e] + v1[e] * v1[e];
  }
#pragma unroll
  for (int m = 1; m < 64; m <<= 1) {
    s1 += __shfl_xor(s1, m, 64);
    s2 += __shfl_xor(s2, m, 64);
  }
  const float mu = s1 * (1.0f / 1024.0f);
  const float var = s2 * (1.0f / 1024.0f) - mu * mu;
  const float rs = rsqrtf(var + 1e-5f);
  u16x8 o0, o1;
#pragma unroll
  for (int e = 0; e < 8; ++e) {
    o0[e] = f2bf(gelu((v0[e] - mu) * rs * qg[c0 + e] + qbeta[c0 + e]));
    o1[e] = f2bf(gelu((v1[e] - mu) * rs * qg[512 + c0 + e] + qbeta[512 + c0 + e]));
  }
  *(u16x8*)(qm + (size_t)j * DDIM + c0) = o0;
  *(u16x8*)(qm + (size_t)j * DDIM + 512 + c0) = o1;
}

// ------------------------- merged V/Q LN; Q-half emits logits only ---------
__global__ __launch_bounds__(256) void k_ln_vq(const u16* __restrict__ h,
                                               const float* __restrict__ v_b,
                                               const float* __restrict__ v_g,
                                               const float* __restrict__ v_beta,
                                               const float* __restrict__ q_b,
                                               const float* __restrict__ q_g,
                                               const float* __restrict__ q_beta,
                                               const u16* __restrict__ qm,
                                               u16* __restrict__ V,
                                               float* __restrict__ logits) {
  __shared__ __align__(16) u16 sqm[NCLS * DDIM];        // 14 KB
  const int tid = threadIdx.x;
  const int lane = tid & 63;
  const int half = (blockIdx.x >= MPD4) ? 1 : 0;
  const int rb = half ? (blockIdx.x - MPD4) : blockIdx.x;
  const int row = rb * 4 + (tid >> 6);
  if (half) {
    for (int i = tid; i < NCLS * DDIM / 8; i += 256)
      *(u16x8*)&sqm[i * 8] = *(const u16x8*)&qm[i * 8];
    __syncthreads();
  }
  if (row >= NROWS) return;                             // no sync after this
  const float* bias = half ? q_b : v_b;
  const float* gain = half ? q_g : v_g;
  const float* bet  = half ? q_beta : v_beta;
  const int c0 = lane * 8;
  const u16* hp = h + (size_t)row * 2048 + (size_t)half * DDIM;
  u16x8 h0 = *(const u16x8*)(hp + c0);
  u16x8 h1 = *(const u16x8*)(hp + 512 + c0);
  float4 a0 = *(const float4*)(bias + c0), a1 = *(const float4*)(bias + c0 + 4);
  float4 a2 = *(const float4*)(bias + 512 + c0), a3 = *(const float4*)(bias + 512 + c0 + 4);
  const float ba[8] = {a0.x, a0.y, a0.z, a0.w, a1.x, a1.y, a1.z, a1.w};
  const float bb[8] = {a2.x, a2.y, a2.z, a2.w, a3.x, a3.y, a3.z, a3.w};
  float v0[8], v1[8];
  float s1 = 0.f, s2 = 0.f;
#pragma unroll
  for (int e = 0; e < 8; ++e) {
    v0[e] = bf2f(h0[e]) + ba[e];
    v1[e] = bf2f(h1[e]) + bb[e];
    s1 += v0[e] + v1[e];
    s2 += v0[e] * v0[e] + v1[e] * v1[e];
  }
#pragma unroll
  for (int m = 1; m < 64; m <<= 1) {
    s1 += __shfl_xor(s1, m, 64);
    s2 += __shfl_xor(s2, m, 64);
  }
  const float mu = s1 * (1.0f / 1024.0f);
  const float var = s2 * (1.0f / 1024.0f) - mu * mu;
  const float rs = rsqrtf(var + 1e-5f);
  float4 g0 = *(const float4*)(gain + c0), g1 = *(const float4*)(gain + c0 + 4);
  float4 g2 = *(const float4*)(gain + 512 + c0), g3 = *(const float4*)(gain + 512 + c0 + 4);
  float4 t0 = *(const float4*)(bet + c0), t1 = *(const float4*)(bet + c0 + 4);
  float4 t2 = *(const float4*)(bet + 512 + c0), t3 = *(const float4*)(bet + 512 + c0 + 4);
  const float ga[8] = {g0.x, g0.y, g0.z, g0.w, g1.x, g1.y, g1.z, g1.w};
  const float gb[8] = {g2.x, g2.y, g2.z, g2.w, g3.x, g3.y, g3.z, g3.w};
  const float ta[8] = {t0.x, t0.y, t0.z, t0.w, t1.x, t1.y, t1.z, t1.w};
  const float tb[8] = {t2.x, t2.y, t2.z, t2.w, t3.x, t3.y, t3.z, t3.w};
  float y0[8], y1[8];
#pragma unroll
  for (int e = 0; e < 8; ++e) {
    y0[e] = gelu((v0[e] - mu) * rs * ga[e] + ta[e]);
    y1[e] = gelu((v1[e] - mu) * rs * gb[e] + tb[e]);
  }
  if (half == 0) {
    u16x8 o0, o1;
#pragma unroll
    for (int e = 0; e < 8; ++e) { o0[e] = f2bf(y0[e]); o1[e] = f2bf(y1[e]); }
    *(u16x8*)(V + (size_t)row * DDIM + c0) = o0;
    *(u16x8*)(V + (size_t)row * DDIM + 512 + c0) = o1;
  } else {
#pragma unroll
    for (int j = 0; j < NCLS; ++j) {
      u16x8 m0 = *(const u16x8*)&sqm[j * DDIM + c0];
      u16x8 m1 = *(const u16x8*)&sqm[j * DDIM + 512 + c0];
      float p = 0.f;
#pragma unroll
      for (int e = 0; e < 8; ++e) p += y0[e] * bf2f(m0[e]) + y1[e] * bf2f(m1[e]);
#pragma unroll
      for (int m = 1; m < 64; m <<= 1) p += __shfl_xor(p, m, 64);
      if (lane == 0) logits[(size_t)row * NCLS + j] = p * 0.03125f;
    }
  }
}

// ------------------------- argmax partials (first-index) -------------------
__global__ __launch_bounds__(256) void k_arg1(const float* __restrict__ c,
                                              float* __restrict__ pv,
                                              int* __restrict__ pi) {
  __shared__ float sv[256 * NCLS];
  __shared__ int   si[256 * NCLS];
  const int t = threadIdx.x;
  float bv[NCLS]; int bi[NCLS];
#pragma unroll
  for (int j = 0; j < NCLS; ++j) { bv[j] = -3.4e38f; bi[j] = 0x7fffffff; }
  for (int n = blockIdx.x * 256 + t; n < NROWS; n += 128 * 256) {
#pragma unroll
    for (int j = 0; j < NCLS; ++j) {
      const float v = c[(size_t)n * NCLS + j];
      if (v > bv[j]) { bv[j] = v; bi[j] = n; }
    }
  }
#pragma unroll
  for (int j = 0; j < NCLS; ++j) { sv[t * NCLS + j] = bv[j]; si[t * NCLS + j] = bi[j]; }
  __syncthreads();
  for (int s = 128; s > 0; s >>= 1) {
    if (t < s) {
#pragma unroll
      for (int j = 0; j < NCLS; ++j) {
        const float v2 = sv[(t + s) * NCLS + j]; const int i2 = si[(t + s) * NCLS + j];
        const float v1 = sv[t * NCLS + j];       const int i1 = si[t * NCLS + j];
        if (v2 > v1 || (v2 == v1 && i2 < i1)) { sv[t * NCLS + j] = v2; si[t * NCLS + j] = i2; }
      }
    }
    __syncthreads();
  }
  if (t < NCLS) { pv[blockIdx.x * NCLS + t] = sv[t]; pi[blockIdx.x * NCLS + t] = si[t]; }
}

// ------------------------- one-pass softmax partials per block -------------
__global__ __launch_bounds__(256) void k_softpart(const float* __restrict__ logits,
                                                  float* __restrict__ Pm,
                                                  float* __restrict__ Ps) {
  __shared__ float sm[256 * NCLS];
  const int t = threadIdx.x;
  float m[NCLS];
#pragma unroll
  for (int j = 0; j < NCLS; ++j) m[j] = -3.4e38f;
  for (int n = blockIdx.x * 256 + t; n < NROWS; n += 128 * 256)
#pragma unroll
    for (int j = 0; j < NCLS; ++j) m[j] = fmaxf(m[j], logits[(size_t)n * NCLS + j]);
#pragma unroll
  for (int j = 0; j < NCLS; ++j) sm[t * NCLS + j] = m[j];
  __syncthreads();
  for (int s = 128; s > 0; s >>= 1) {
    if (t < s)
#pragma unroll
      for (int j = 0; j < NCLS; ++j)
        sm[t * NCLS + j] = fmaxf(sm[t * NCLS + j], sm[(t + s) * NCLS + j]);
    __syncthreads();
  }
  float mloc[NCLS];
#pragma unroll
  for (int j = 0; j < NCLS; ++j) mloc[j] = sm[j];
  __syncthreads();
  float s[NCLS];
#pragma unroll
  for (int j = 0; j < NCLS; ++j) s[j] = 0.f;
  for (int n = blockIdx.x * 256 + t; n < NROWS; n += 128 * 256)
#pragma unroll
    for (int j = 0; j < NCLS; ++j) s[j] += expf(logits[(size_t)n * NCLS + j] - mloc[j]);
#pragma unroll
  for (int j = 0; j < NCLS; ++j) sm[t * NCLS + j] = s[j];
  __syncthreads();
  for (int st = 128; st > 0; st >>= 1) {
    if (t < st)
#pragma unroll
      for (int j = 0; j < NCLS; ++j) sm[t * NCLS + j] += sm[(t + st) * NCLS + j];
    __syncthreads();
  }
  if (t < NCLS) { Pm[blockIdx.x * NCLS + t] = mloc[t]; Ps[blockIdx.x * NCLS + t] = sm[t]; }
}

// ------------------------- B-partials = A^T V, fused A-write + rescale-fin -
__global__ __launch_bounds__(256) void k_bpart(const float* __restrict__ logits,
                                               const float* __restrict__ Pm,
                                               const float* __restrict__ Ps,
                                               const u16* __restrict__ V,
                                               float* __restrict__ Aout,
                                               float* __restrict__ Pb) {
  __shared__ float sA[98 * NCLS];
  __shared__ float sM[NCLS], sR[NCLS];
  const int t = threadIdx.x;
  if (t < NCLS) {
    float M = -3.4e38f;
    for (int b = 0; b < 128; ++b) M = fmaxf(M, Pm[b * NCLS + t]);
    float S = 0.f;
    for (int b = 0; b < 128; ++b) S += Ps[b * NCLS + t] * expf(Pm[b * NCLS + t] - M);
    sM[t] = M; sR[t] = 1.0f / S;
  }
  __syncthreads();
  const int n0 = blockIdx.x * 98;
  int cnt = NROWS - n0;
  cnt = cnt < 0 ? 0 : (cnt > 98 ? 98 : cnt);
  for (int idx = t; idx < cnt * NCLS; idx += 256) {
    const int j = idx % NCLS;
    const float a = expf(logits[(size_t)n0 * NCLS + idx] - sM[j]) * sR[j];
    sA[idx] = a;
    Aout[(size_t)n0 * NCLS + idx] = a;
  }
  __syncthreads();
  float acc[NCLS][4] = {};
  for (int r = 0; r < cnt; ++r) {
    u16x4 vv = *(const u16x4*)&V[(size_t)(n0 + r) * DDIM + t * 4];
    const float f0 = bf2f(vv[0]), f1 = bf2f(vv[1]), f2 = bf2f(vv[2]), f3 = bf2f(vv[3]);
#pragma unroll
    for (int j = 0; j < NCLS; ++j) {
      const float a = sA[r * NCLS + j];
      acc[j][0] += a * f0; acc[j][1] += a * f1; acc[j][2] += a * f2; acc[j][3] += a * f3;
    }
  }
#pragma unroll
  for (int j = 0; j < NCLS; ++j) {
    f32x4 o = {acc[j][0], acc[j][1], acc[j][2], acc[j][3]};
    *(f32x4*)&Pb[((size_t)blockIdx.x * NCLS + j) * DDIM + t * 4] = o;
  }
}

__global__ void k_bred(const float* __restrict__ Pb, float* __restrict__ Bout) {
  const int idx = blockIdx.x * 256 + threadIdx.x;
  if (idx >= NCLS * DDIM) return;
  float s = 0.f;
  for (int p = 0; p < 512; ++p) s += Pb[(size_t)p * NCLS * DDIM + idx];
  Bout[idx] = s;
}

// ------------------------- C[o] = <B, head_w[o]> + head_b[o] ---------------
__global__ __launch_bounds__(256) void k_head(const float* __restrict__ Bmat,
                                              const float* __restrict__ hw,
                                              const float* __restrict__ hb,
                                              float* __restrict__ Cout) {
  const int o = blockIdx.x, t = threadIdx.x;
  float p = 0.f;
  for (int idx = t; idx < NCLS * DDIM; idx += 256)
    p += Bmat[idx] * hw[(size_t)o * NCLS * DDIM + idx];
#pragma unroll
  for (int m = 1; m < 64; m <<= 1) p += __shfl_xor(p, m, 64);
  __shared__ float w[4];
  if ((t & 63) == 0) w[t >> 6] = p;
  __syncthreads();
  if (t == 0) Cout[o] = w[0] + w[1] + w[2] + w[3] + hb[o];
}

// ---------------------------------------------------------------------------
extern "C" void kernel_launch(void* const* d_in, const int* in_sizes, int n_in,
                              void* d_out, int out_size, void* d_ws, size_t ws_size,
                              hipStream_t stream) {
  const float* features   = (const float*)d_in[0];
  const float* c_in       = (const float*)d_in[1];
  const float* key_w      = (const float*)d_in[2];
  const float* key_b      = (const float*)d_in[3];
  const float* key_g      = (const float*)d_in[4];
  const float* key_beta   = (const float*)d_in[5];
  const float* query_w    = (const float*)d_in[6];
  const float* query_b    = (const float*)d_in[7];
  const float* query_g    = (const float*)d_in[8];
  const float* query_beta = (const float*)d_in[9];
  const float* value_w    = (const float*)d_in[10];
  const float* value_b    = (const float*)d_in[11];
  const float* value_g    = (const float*)d_in[12];
  const float* value_beta = (const float*)d_in[13];
  const float* head_w     = (const float*)d_in[14];
  const float* head_b     = (const float*)d_in[15];

  char* ws = (char*)d_ws;
  const size_t SZB = (size_t)MP * DDIM * 2;             // 102,760,448 B
  u16* Xb   = (u16*)ws;                                 // [MP,1024] features bf16
  u16* HbK  = (u16*)(ws + SZB);                         // [MP,1024] pre-LN K
  u16* HbVQ = Xb;                                       // [MP,2048] aliases Xb|HbK (both dead)
  u16* Kb   = (u16*)(ws + 2 * SZB);                     // [MP,1024]
  u16* Vb   = Kb;                                       // reuse after VQ-GEMM
  size_t off = 3 * SZB;
  u16* Wk  = (u16*)(ws + off); off += (size_t)DDIM * DDIM * 2;
  u16* Wvq = (u16*)(ws + off); off += (size_t)2 * DDIM * DDIM * 2;
  float* logits = (float*)(ws + off); off += ((size_t)NROWS * NCLS * 4 + 255) & ~(size_t)255;
  float* Pb  = (float*)(ws + off); off += (size_t)512 * NCLS * DDIM * 4;
  u16* qm    = (u16*)(ws + off); off += ((size_t)NCLS * DDIM * 2 + 255) & ~(size_t)255;
  float* Pmax = (float*)(ws + off); off += ((size_t)128 * NCLS * 4 + 255) & ~(size_t)255;
  float* Psum = (float*)(ws + off); off += ((size_t)128 * NCLS * 4 + 255) & ~(size_t)255;
  float* argv = (float*)(ws + off); off += ((size_t)128 * NCLS * 4 + 255) & ~(size_t)255;
  int*   argi = (int*)  (ws + off); off += ((size_t)128 * NCLS * 4 + 255) & ~(size_t)255;

  float* Cout = (float*)d_out;                          // [7]
  float* Aout = Cout + NCLS;                            // [50000,7]
  float* Bout = Aout + (size_t)NROWS * NCLS;            // [7,1024]

  // argmax partials + dtype converts
  k_arg1<<<128, 256, 0, stream>>>(c_in, argv, argi);
  k_convw<<<384, 256, 0, stream>>>(key_w, value_w, query_w, Wk, Wvq);
  k_convert<<<2048, 256, 0, stream>>>(features, Xb, MP, NROWS);

  // K chain: 256^2 phased GEMM (196 x 4 tiles), then LN (zero-pads to MP)
  k_gemm256<<<784, 512, 131072, stream>>>(Xb, Wk, HbK, 2, 1024);
  k_ln_k<<<MPD4, 256, 0, stream>>>(HbK, key_b, key_g, key_beta, Kb);

  // merged V|Q GEMM: 256^2 phased kernel (196 x 8 tiles); HbVQ aliases Xb|HbK
  k_gemm256<<<1568, 512, 131072, stream>>>(Kb, Wvq, HbVQ, 3, 2048);
  k_qmax2<<<NCLS, 64, 0, stream>>>(argv, argi, HbVQ, query_b, query_g, query_beta, qm);
  k_ln_vq<<<2 * MPD4, 256, 0, stream>>>(HbVQ, value_b, value_g, value_beta,
                                        query_b, query_g, query_beta, qm, Vb, logits);

  // softmax over axis 0: one-pass partials, rescale-fin in consumer
  k_softpart<<<128, 256, 0, stream>>>(logits, Pmax, Psum);

  // B = A^T V (A materialized on the fly), head contraction
  k_bpart<<<512, 256, 0, stream>>>(logits, Pmax, Psum, Vb, Aout, Pb);
  k_bred<<<28, 256, 0, stream>>>(Pb, Bout);
  k_head<<<NCLS, 256, 0, stream>>>(Bout, head_w, head_b, Cout);
}

// Round 10
// 667.892 us; speedup vs baseline: 1.6946x; 1.0153x over previous
//
#include <hip/hip_runtime.h>

// ---------------------------------------------------------------------------
// AttDual round 9: 256x256/BK=64 phased GEMM with COUNTED final vmcnt(4):
// B single-buffered (read only in PH1 -> restaged PH2), A 3-buffer ring
// (staged 2 K-tiles ahead at PH3, left in flight across the barrier).
// Same 128 KiB LDS. Everything else identical to round 8.
// ---------------------------------------------------------------------------

typedef unsigned short u16;
typedef __attribute__((ext_vector_type(8))) short          bf16x8;
typedef __attribute__((ext_vector_type(8))) unsigned short u16x8;
typedef __attribute__((ext_vector_type(4))) unsigned short u16x4;
typedef __attribute__((ext_vector_type(4))) float          f32x4;

#define DDIM  1024
#define NROWS 50000
#define MP    50176      // 196 * 256 padded rows (zeros)
#define NCLS  7
#define MPD4  12544      // MP/4

__device__ __forceinline__ u16 f2bf(float f) {          // RNE fp32 -> bf16
  unsigned u = __float_as_uint(f);
  u = (u + 0x7FFFu + ((u >> 16) & 1u)) >> 16;
  return (u16)u;
}
__device__ __forceinline__ float bf2f(u16 h) {
  return __uint_as_float(((unsigned)h) << 16);
}
__device__ __forceinline__ float gelu(float x) {
  return 0.5f * x * (1.0f + erff(x * 0.70710678118654752f));
}

__device__ __forceinline__ void load16_lds(const u16* g, u16* l) {
  __builtin_amdgcn_global_load_lds(
      (const __attribute__((address_space(1))) unsigned int*)(const void*)g,
      (__attribute__((address_space(3))) unsigned int*)(void*)l, 16, 0, 0);
}

#define MFMA_(a, b, c) __builtin_amdgcn_mfma_f32_16x16x32_bf16(a, b, c, 0, 0, 0)

// ------------------------- fp32 -> bf16 convert (features, +row zero-pad) --
__global__ __launch_bounds__(256) void k_convert(const float* __restrict__ src,
                                                 u16* __restrict__ dst,
                                                 int rows_total, int rows_valid) {
  const size_t total = (size_t)rows_total * DDIM / 8;
  const size_t stride = (size_t)gridDim.x * blockDim.x;
  for (size_t i = (size_t)blockIdx.x * blockDim.x + threadIdx.x; i < total; i += stride) {
    const size_t e = i * 8;
    const int row = (int)(e >> 10);
    u16x8 o = {0, 0, 0, 0, 0, 0, 0, 0};
    if (row < rows_valid) {
      const float4* p = (const float4*)(src + e);
      float4 f0 = p[0], f1 = p[1];
      o[0] = f2bf(f0.x); o[1] = f2bf(f0.y); o[2] = f2bf(f0.z); o[3] = f2bf(f0.w);
      o[4] = f2bf(f1.x); o[5] = f2bf(f1.y); o[6] = f2bf(f1.z); o[7] = f2bf(f1.w);
    }
    *(u16x8*)(dst + e) = o;
  }
}

// ------------------------- 3 weight matrices -> Wk, Wvq=concat(Wv,Wq) ------
__global__ __launch_bounds__(256) void k_convw(const float* __restrict__ kw,
                                               const float* __restrict__ vw,
                                               const float* __restrict__ qw,
                                               u16* __restrict__ Wk,
                                               u16* __restrict__ Wvq) {
  const int w = blockIdx.x >> 7;
  const int b = blockIdx.x & 127;
  const float* src = (w == 0) ? kw : (w == 1) ? vw : qw;
  u16* dst = (w == 0) ? Wk : (Wvq + (size_t)(w - 1) * DDIM * DDIM);
  for (int i = b * 256 + threadIdx.x; i < DDIM * DDIM / 8; i += 128 * 256) {
    const float4* p = (const float4*)(src + (size_t)i * 8);
    float4 f0 = p[0], f1 = p[1];
    u16x8 o;
    o[0] = f2bf(f0.x); o[1] = f2bf(f0.y); o[2] = f2bf(f0.z); o[3] = f2bf(f0.w);
    o[4] = f2bf(f1.x); o[5] = f2bf(f1.y); o[6] = f2bf(f1.z); o[7] = f2bf(f1.w);
    *(u16x8*)(dst + (size_t)i * 8) = o;
  }
}

// ------------------------- 256^2 phased GEMM (bf16 A, bf16 B^T layout) -----
// C[m,n] = sum_k A[m,k]*B[n,k].  M = 196 tiles; N-tiles = 1<<lnn; ldc given.
// 8 waves: wr=wid>>2 (A-half), wc=wid&3 (64-col group, B-half wc>>1).
// LDS: A = 3-ring x 2 halves x (128x64 bf16) = 96 KiB; B = 1 buf = 32 KiB.
// Schedule/iteration (4 phases, raw s_barrier):
//   PH1: read all B-frags + A rows 0-1, MFMA; (B buffer dead after this)
//   PH2: stage B(kt+1) into the single B buffer; MFMA rows 2-3
//   PH3: stage A(kt+2) into ring slot (kt+2)%3; MFMA rows 4-5
//   PH4: MFMA rows 6-7; s_waitcnt vmcnt(4) (A(kt+2) stays in flight) + barrier
__global__ __launch_bounds__(512, 2) void k_gemm256(const u16* __restrict__ A,
                                                    const u16* __restrict__ Bw,
                                                    u16* __restrict__ C,
                                                    int lnn, int ldc) {
  extern __shared__ __align__(16) u16 smem[];
  u16* Abase = smem;                 // [3][2][8192]
  u16* Bbase = smem + 49152;         // [2][8192]
  const int tid  = threadIdx.x;
  const int lane = tid & 63;
  const int wid  = tid >> 6;
  const int wr = wid >> 2;           // 0..1  : A half (128 rows)
  const int wc = wid & 3;            // 0..3  : 64-col group
  const int bh = wc >> 1;            // B half this wave reads
  const int bl = (wc & 1) * 64;      // local n-row base within B half
  const int fr = lane & 15;
  const int T  = lane >> 4;
  const int cpx = gridDim.x >> 3;                              // nwg % 8 == 0
  const int v  = (blockIdx.x & 7) * cpx + (blockIdx.x >> 3);
  const int m0 = (v >> lnn) * 256;
  const int n0 = (v & ((1 << lnn) - 1)) * 256;

  f32x4 acc[8][4] = {};

#define STAGE_A(KT, BB) do {                                                   \
    _Pragma("unroll") for (int h_ = 0; h_ < 2; ++h_)                           \
      _Pragma("unroll") for (int l_ = 0; l_ < 2; ++l_) {                       \
        const int s_ = l_ * 512 + tid;                                         \
        const int r_ = s_ >> 3;                                                \
        const int c_ = (s_ & 7) ^ (r_ & 7);                                    \
        load16_lds(A + (size_t)(m0 + h_ * 128 + r_) * DDIM + (KT) * 64 + c_ * 8, \
                   Abase + (BB) * 16384 + h_ * 8192 + s_ * 8);                 \
      } } while (0)

#define STAGE_B(KT) do {                                                       \
    _Pragma("unroll") for (int h_ = 0; h_ < 2; ++h_)                           \
      _Pragma("unroll") for (int l_ = 0; l_ < 2; ++l_) {                       \
        const int s_ = l_ * 512 + tid;                                         \
        const int r_ = s_ >> 3;                                                \
        const int c_ = (s_ & 7) ^ (r_ & 7);                                    \
        load16_lds(Bw + (size_t)(n0 + h_ * 128 + r_) * DDIM + (KT) * 64 + c_ * 8, \
                   Bbase + h_ * 8192 + s_ * 8);                                \
      } } while (0)

#define PHASE_A(p) do {                                                        \
    bf16x8 afr[4];                                                             \
    _Pragma("unroll") for (int ks = 0; ks < 2; ++ks)                           \
      _Pragma("unroll") for (int ii = 0; ii < 2; ++ii) {                       \
        const int R = ((p) * 2 + ii) * 16 + fr;                                \
        afr[ks * 2 + ii] = *(const bf16x8*)&Ap[R * 64 + (((ks * 4 + T) ^ (R & 7)) << 3)]; \
      }                                                                        \
    __builtin_amdgcn_s_setprio(1);                                             \
    _Pragma("unroll") for (int ks = 0; ks < 2; ++ks)                           \
      _Pragma("unroll") for (int ii = 0; ii < 2; ++ii)                         \
        _Pragma("unroll") for (int j = 0; j < 4; ++j)                          \
          acc[(p) * 2 + ii][j] = MFMA_(afr[ks * 2 + ii], bfr[ks * 4 + j],      \
                                       acc[(p) * 2 + ii][j]);                  \
    __builtin_amdgcn_s_setprio(0);                                             \
  } while (0)

#define BARP() asm volatile("s_barrier" ::: "memory")

  // prologue: A(0)->slot0, B(0), A(1)->slot1 LAST; counted wait leaves A(1)
  STAGE_A(0, 0);
  STAGE_B(0);
  STAGE_A(1, 1);
  asm volatile("s_waitcnt vmcnt(4)\n\ts_barrier" ::: "memory");

  for (int kt = 0; kt < 16; ++kt) {
    const u16* Ap = Abase + (kt % 3) * 16384 + wr * 8192;
    const u16* Bp = Bbase + bh * 8192;
    bf16x8 bfr[8];
    // PH1: read all B-frags (B buffer dead afterwards) + A rows 0-1
#pragma unroll
    for (int ks = 0; ks < 2; ++ks)
#pragma unroll
      for (int j = 0; j < 4; ++j) {
        const int R = bl + j * 16 + fr;
        bfr[ks * 4 + j] = *(const bf16x8*)&Bp[R * 64 + (((ks * 4 + T) ^ (R & 7)) << 3)];
      }
    PHASE_A(0);
    BARP();
    // PH2: restage the single B buffer with B(kt+1)
    if (kt < 15) STAGE_B(kt + 1);
    PHASE_A(1);
    BARP();
    // PH3: stage A(kt+2) into ring slot (kt+2)%3 (dead since iter kt-1)
    if (kt < 14) STAGE_A(kt + 2, (kt + 2) % 3);
    PHASE_A(2);
    BARP();
    // PH4: counted wait — drain A(kt+1)+B(kt+1), leave A(kt+2) in flight
    PHASE_A(3);
    if (kt < 14)
      asm volatile("s_waitcnt vmcnt(4)\n\ts_barrier" ::: "memory");
    else if (kt == 14)
      asm volatile("s_waitcnt vmcnt(0)\n\ts_barrier" ::: "memory");
  }
#undef STAGE_A
#undef STAGE_B
#undef PHASE_A
#undef BARP

  // epilogue: C write
#pragma unroll
  for (int i = 0; i < 8; ++i)
#pragma unroll
    for (int j = 0; j < 4; ++j) {
      const size_t base = (size_t)(m0 + wr * 128 + i * 16 + T * 4) * ldc
                        + (n0 + wc * 64 + j * 16 + fr);
#pragma unroll
      for (int r = 0; r < 4; ++r)
        C[base + (size_t)r * ldc] = f2bf(acc[i][j][r]);
    }
}

// ------------------------- bias + LN + GELU for K (zero-pads rows) ---------
__global__ __launch_bounds__(256) void k_ln_k(const u16* __restrict__ h,
                                              const float* __restrict__ bias,
                                              const float* __restrict__ g,
                                              const float* __restrict__ beta,
                                              u16* __restrict__ out) {
  const int lane = threadIdx.x & 63;
  const int row = blockIdx.x * 4 + (threadIdx.x >> 6);
  const int c0 = lane * 8;
  u16x8* op0 = (u16x8*)(out + (size_t)row * DDIM + c0);
  u16x8* op1 = (u16x8*)(out + (size_t)row * DDIM + 512 + c0);
  if (row >= NROWS) {
    u16x8 z = {0, 0, 0, 0, 0, 0, 0, 0};
    *op0 = z; *op1 = z;
    return;
  }
  u16x8 h0 = *(const u16x8*)(h + (size_t)row * DDIM + c0);
  u16x8 h1 = *(const u16x8*)(h + (size_t)row * DDIM + 512 + c0);
  float4 a0 = *(const float4*)(bias + c0), a1 = *(const float4*)(bias + c0 + 4);
  float4 a2 = *(const float4*)(bias + 512 + c0), a3 = *(const float4*)(bias + 512 + c0 + 4);
  const float ba[8] = {a0.x, a0.y, a0.z, a0.w, a1.x, a1.y, a1.z, a1.w};
  const float bb[8] = {a2.x, a2.y, a2.z, a2.w, a3.x, a3.y, a3.z, a3.w};
  float v0[8], v1[8];
  float s1 = 0.f, s2 = 0.f;
#pragma unroll
  for (int e = 0; e < 8; ++e) {
    v0[e] = bf2f(h0[e]) + ba[e];
    v1[e] = bf2f(h1[e]) + bb[e];
    s1 += v0[e] + v1[e];
    s2 += v0[e] * v0[e] + v1[e] * v1[e];
  }
#pragma unroll
  for (int m = 1; m < 64; m <<= 1) {
    s1 += __shfl_xor(s1, m, 64);
    s2 += __shfl_xor(s2, m, 64);
  }
  const float mu = s1 * (1.0f / 1024.0f);
  const float var = s2 * (1.0f / 1024.0f) - mu * mu;
  const float rs = rsqrtf(var + 1e-5f);
  float4 g0 = *(const float4*)(g + c0), g1 = *(const float4*)(g + c0 + 4);
  float4 g2 = *(const float4*)(g + 512 + c0), g3 = *(const float4*)(g + 512 + c0 + 4);
  float4 t0 = *(const float4*)(beta + c0), t1 = *(const float4*)(beta + c0 + 4);
  float4 t2 = *(const float4*)(beta + 512 + c0), t3 = *(const float4*)(beta + 512 + c0 + 4);
  const float ga[8] = {g0.x, g0.y, g0.z, g0.w, g1.x, g1.y, g1.z, g1.w};
  const float gb[8] = {g2.x, g2.y, g2.z, g2.w, g3.x, g3.y, g3.z, g3.w};
  const float ta[8] = {t0.x, t0.y, t0.z, t0.w, t1.x, t1.y, t1.z, t1.w};
  const float tb[8] = {t2.x, t2.y, t2.z, t2.w, t3.x, t3.y, t3.z, t3.w};
  u16x8 o0, o1;
#pragma unroll
  for (int e = 0; e < 8; ++e) {
    o0[e] = f2bf(gelu((v0[e] - mu) * rs * ga[e] + ta[e]));
    o1[e] = f2bf(gelu((v1[e] - mu) * rs * gb[e] + tb[e]));
  }
  *op0 = o0; *op1 = o1;
}

// ------------------------- q_max from HbVQ rows (fin of argmax inside) -----
__global__ __launch_bounds__(64) void k_qmax2(const float* __restrict__ argv,
                                              const int* __restrict__ argi,
                                              const u16* __restrict__ hvq,
                                              const float* __restrict__ qb,
                                              const float* __restrict__ qg,
                                              const float* __restrict__ qbeta,
                                              u16* __restrict__ qm) {
  const int j = blockIdx.x;
  const int lane = threadIdx.x;
  float bv = -3.4e38f; int bi = 0x7fffffff;
  for (int p = lane; p < 128; p += 64) {
    const float v = argv[p * NCLS + j];
    const int   i = argi[p * NCLS + j];
    if (v > bv || (v == bv && i < bi)) { bv = v; bi = i; }
  }
#pragma unroll
  for (int m = 1; m < 64; m <<= 1) {
    const float ov = __shfl_xor(bv, m, 64);
    const int   oi = __shfl_xor(bi, m, 64);
    if (ov > bv || (ov == bv && oi < bi)) { bv = ov; bi = oi; }
  }
  const int row = bi;
  const int c0 = lane * 8;
  const u16* hp = hvq + (size_t)row * 2048 + DDIM;      // Q-half
  u16x8 h0 = *(const u16x8*)(hp + c0);
  u16x8 h1 = *(const u16x8*)(hp + 512 + c0);
  float v0[8], v1[8];
  float s1 = 0.f, s2 = 0.f;
#pragma unroll
  for (int e = 0; e < 8; ++e) {
    v0[e] = bf2f(h0[e]) + qb[c0 + e];
    v1[e] = bf2f(h1[e]) + qb[512 + c0 + e];
    s1 += v0[e] + v1[e];
    s2 += v0[e] * v0[e] + v1[e] * v1[e];
  }
#pragma unroll
  for (int m = 1; m < 64; m <<= 1) {
    s1 += __shfl_xor(s1, m, 64);
    s2 += __shfl_xor(s2, m, 64);
  }
  const float mu = s1 * (1.0f / 1024.0f);
  const float var = s2 * (1.0f / 1024.0f) - mu * mu;
  const float rs = rsqrtf(var + 1e-5f);
  u16x8 o0, o1;
#pragma unroll
  for (int e = 0; e < 8; ++e) {
    o0[e] = f2bf(gelu((v0[e] - mu) * rs * qg[c0 + e] + qbeta[c0 + e]));
    o1[e] = f2bf(gelu((v1[e] - mu) * rs * qg[512 + c0 + e] + qbeta[512 + c0 + e]));
  }
  *(u16x8*)(qm + (size_t)j * DDIM + c0) = o0;
  *(u16x8*)(qm + (size_t)j * DDIM + 512 + c0) = o1;
}

// ------------------------- merged V/Q LN; Q-half emits logits only ---------
__global__ __launch_bounds__(256) void k_ln_vq(const u16* __restrict__ h,
                                               const float* __restrict__ v_b,
                                               const float* __restrict__ v_g,
                                               const float* __restrict__ v_beta,
                                               const float* __restrict__ q_b,
                                               const float* __restrict__ q_g,
                                               const float* __restrict__ q_beta,
                                               const u16* __restrict__ qm,
                                               u16* __restrict__ V,
                                               float* __restrict__ logits) {
  __shared__ __align__(16) u16 sqm[NCLS * DDIM];        // 14 KB
  const int tid = threadIdx.x;
  const int lane = tid & 63;
  const int half = (blockIdx.x >= MPD4) ? 1 : 0;
  const int rb = half ? (blockIdx.x - MPD4) : blockIdx.x;
  const int row = rb * 4 + (tid >> 6);
  if (half) {
    for (int i = tid; i < NCLS * DDIM / 8; i += 256)
      *(u16x8*)&sqm[i * 8] = *(const u16x8*)&qm[i * 8];
    __syncthreads();
  }
  if (row >= NROWS) return;                             // no sync after this
  const float* bias = half ? q_b : v_b;
  const float* gain = half ? q_g : v_g;
  const float* bet  = half ? q_beta : v_beta;
  const int c0 = lane * 8;
  const u16* hp = h + (size_t)row * 2048 + (size_t)half * DDIM;
  u16x8 h0 = *(const u16x8*)(hp + c0);
  u16x8 h1 = *(const u16x8*)(hp + 512 + c0);
  float4 a0 = *(const float4*)(bias + c0), a1 = *(const float4*)(bias + c0 + 4);
  float4 a2 = *(const float4*)(bias + 512 + c0), a3 = *(const float4*)(bias + 512 + c0 + 4);
  const float ba[8] = {a0.x, a0.y, a0.z, a0.w, a1.x, a1.y, a1.z, a1.w};
  const float bb[8] = {a2.x, a2.y, a2.z, a2.w, a3.x, a3.y, a3.z, a3.w};
  float v0[8], v1[8];
  float s1 = 0.f, s2 = 0.f;
#pragma unroll
  for (int e = 0; e < 8; ++e) {
    v0[e] = bf2f(h0[e]) + ba[e];
    v1[e] = bf2f(h1[e]) + bb[e];
    s1 += v0[e] + v1[e];
    s2 += v0[e] * v0[e] + v1[e] * v1[e];
  }
#pragma unroll
  for (int m = 1; m < 64; m <<= 1) {
    s1 += __shfl_xor(s1, m, 64);
    s2 += __shfl_xor(s2, m, 64);
  }
  const float mu = s1 * (1.0f / 1024.0f);
  const float var = s2 * (1.0f / 1024.0f) - mu * mu;
  const float rs = rsqrtf(var + 1e-5f);
  float4 g0 = *(const float4*)(gain + c0), g1 = *(const float4*)(gain + c0 + 4);
  float4 g2 = *(const float4*)(gain + 512 + c0), g3 = *(const float4*)(gain + 512 + c0 + 4);
  float4 t0 = *(const float4*)(bet + c0), t1 = *(const float4*)(bet + c0 + 4);
  float4 t2 = *(const float4*)(bet + 512 + c0), t3 = *(const float4*)(bet + 512 + c0 + 4);
  const float ga[8] = {g0.x, g0.y, g0.z, g0.w, g1.x, g1.y, g1.z, g1.w};
  const float gb[8] = {g2.x, g2.y, g2.z, g2.w, g3.x, g3.y, g3.z, g3.w};
  const float ta[8] = {t0.x, t0.y, t0.z, t0.w, t1.x, t1.y, t1.z, t1.w};
  const float tb[8] = {t2.x, t2.y, t2.z, t2.w, t3.x, t3.y, t3.z, t3.w};
  float y0[8], y1[8];
#pragma unroll
  for (int e = 0; e < 8; ++e) {
    y0[e] = gelu((v0[e] - mu) * rs * ga[e] + ta[e]);
    y1[e] = gelu((v1[e] - mu) * rs * gb[e] + tb[e]);
  }
  if (half == 0) {
    u16x8 o0, o1;
#pragma unroll
    for (int e = 0; e < 8; ++e) { o0[e] = f2bf(y0[e]); o1[e] = f2bf(y1[e]); }
    *(u16x8*)(V + (size_t)row * DDIM + c0) = o0;
    *(u16x8*)(V + (size_t)row * DDIM + 512 + c0) = o1;
  } else {
#pragma unroll
    for (int j = 0; j < NCLS; ++j) {
      u16x8 m0 = *(const u16x8*)&sqm[j * DDIM + c0];
      u16x8 m1 = *(const u16x8*)&sqm[j * DDIM + 512 + c0];
      float p = 0.f;
#pragma unroll
      for (int e = 0; e < 8; ++e) p += y0[e] * bf2f(m0[e]) + y1[e] * bf2f(m1[e]);
#pragma unroll
      for (int m = 1; m < 64; m <<= 1) p += __shfl_xor(p, m, 64);
      if (lane == 0) logits[(size_t)row * NCLS + j] = p * 0.03125f;
    }
  }
}

// ------------------------- argmax partials (first-index) -------------------
__global__ __launch_bounds__(256) void k_arg1(const float* __restrict__ c,
                                              float* __restrict__ pv,
                                              int* __restrict__ pi) {
  __shared__ float sv[256 * NCLS];
  __shared__ int   si[256 * NCLS];
  const int t = threadIdx.x;
  float bv[NCLS]; int bi[NCLS];
#pragma unroll
  for (int j = 0; j < NCLS; ++j) { bv[j] = -3.4e38f; bi[j] = 0x7fffffff; }
  for (int n = blockIdx.x * 256 + t; n < NROWS; n += 128 * 256) {
#pragma unroll
    for (int j = 0; j < NCLS; ++j) {
      const float v = c[(size_t)n * NCLS + j];
      if (v > bv[j]) { bv[j] = v; bi[j] = n; }
    }
  }
#pragma unroll
  for (int j = 0; j < NCLS; ++j) { sv[t * NCLS + j] = bv[j]; si[t * NCLS + j] = bi[j]; }
  __syncthreads();
  for (int s = 128; s > 0; s >>= 1) {
    if (t < s) {
#pragma unroll
      for (int j = 0; j < NCLS; ++j) {
        const float v2 = sv[(t + s) * NCLS + j]; const int i2 = si[(t + s) * NCLS + j];
        const float v1 = sv[t * NCLS + j];       const int i1 = si[t * NCLS + j];
        if (v2 > v1 || (v2 == v1 && i2 < i1)) { sv[t * NCLS + j] = v2; si[t * NCLS + j] = i2; }
      }
    }
    __syncthreads();
  }
  if (t < NCLS) { pv[blockIdx.x * NCLS + t] = sv[t]; pi[blockIdx.x * NCLS + t] = si[t]; }
}

// ------------------------- one-pass softmax partials per block -------------
__global__ __launch_bounds__(256) void k_softpart(const float* __restrict__ logits,
                                                  float* __restrict__ Pm,
                                                  float* __restrict__ Ps) {
  __shared__ float sm[256 * NCLS];
  const int t = threadIdx.x;
  float m[NCLS];
#pragma unroll
  for (int j = 0; j < NCLS; ++j) m[j] = -3.4e38f;
  for (int n = blockIdx.x * 256 + t; n < NROWS; n += 128 * 256)
#pragma unroll
    for (int j = 0; j < NCLS; ++j) m[j] = fmaxf(m[j], logits[(size_t)n * NCLS + j]);
#pragma unroll
  for (int j = 0; j < NCLS; ++j) sm[t * NCLS + j] = m[j];
  __syncthreads();
  for (int s = 128; s > 0; s >>= 1) {
    if (t < s)
#pragma unroll
      for (int j = 0; j < NCLS; ++j)
        sm[t * NCLS + j] = fmaxf(sm[t * NCLS + j], sm[(t + s) * NCLS + j]);
    __syncthreads();
  }
  float mloc[NCLS];
#pragma unroll
  for (int j = 0; j < NCLS; ++j) mloc[j] = sm[j];
  __syncthreads();
  float s[NCLS];
#pragma unroll
  for (int j = 0; j < NCLS; ++j) s[j] = 0.f;
  for (int n = blockIdx.x * 256 + t; n < NROWS; n += 128 * 256)
#pragma unroll
    for (int j = 0; j < NCLS; ++j) s[j] += expf(logits[(size_t)n * NCLS + j] - mloc[j]);
#pragma unroll
  for (int j = 0; j < NCLS; ++j) sm[t * NCLS + j] = s[j];
  __syncthreads();
  for (int st = 128; st > 0; st >>= 1) {
    if (t < st)
#pragma unroll
      for (int j = 0; j < NCLS; ++j) sm[t * NCLS + j] += sm[(t + st) * NCLS + j];
    __syncthreads();
  }
  if (t < NCLS) { Pm[blockIdx.x * NCLS + t] = mloc[t]; Ps[blockIdx.x * NCLS + t] = sm[t]; }
}

// ------------------------- B-partials = A^T V, fused A-write + rescale-fin -
__global__ __launch_bounds__(256) void k_bpart(const float* __restrict__ logits,
                                               const float* __restrict__ Pm,
                                               const float* __restrict__ Ps,
                                               const u16* __restrict__ V,
                                               float* __restrict__ Aout,
                                               float* __restrict__ Pb) {
  __shared__ float sA[98 * NCLS];
  __shared__ float sM[NCLS], sR[NCLS];
  const int t = threadIdx.x;
  if (t < NCLS) {
    float M = -3.4e38f;
    for (int b = 0; b < 128; ++b) M = fmaxf(M, Pm[b * NCLS + t]);
    float S = 0.f;
    for (int b = 0; b < 128; ++b) S += Ps[b * NCLS + t] * expf(Pm[b * NCLS + t] - M);
    sM[t] = M; sR[t] = 1.0f / S;
  }
  __syncthreads();
  const int n0 = blockIdx.x * 98;
  int cnt = NROWS - n0;
  cnt = cnt < 0 ? 0 : (cnt > 98 ? 98 : cnt);
  for (int idx = t; idx < cnt * NCLS; idx += 256) {
    const int j = idx % NCLS;
    const float a = expf(logits[(size_t)n0 * NCLS + idx] - sM[j]) * sR[j];
    sA[idx] = a;
    Aout[(size_t)n0 * NCLS + idx] = a;
  }
  __syncthreads();
  float acc[NCLS][4] = {};
  for (int r = 0; r < cnt; ++r) {
    u16x4 vv = *(const u16x4*)&V[(size_t)(n0 + r) * DDIM + t * 4];
    const float f0 = bf2f(vv[0]), f1 = bf2f(vv[1]), f2 = bf2f(vv[2]), f3 = bf2f(vv[3]);
#pragma unroll
    for (int j = 0; j < NCLS; ++j) {
      const float a = sA[r * NCLS + j];
      acc[j][0] += a * f0; acc[j][1] += a * f1; acc[j][2] += a * f2; acc[j][3] += a * f3;
    }
  }
#pragma unroll
  for (int j = 0; j < NCLS; ++j) {
    f32x4 o = {acc[j][0], acc[j][1], acc[j][2], acc[j][3]};
    *(f32x4*)&Pb[((size_t)blockIdx.x * NCLS + j) * DDIM + t * 4] = o;
  }
}

__global__ void k_bred(const float* __restrict__ Pb, float* __restrict__ Bout) {
  const int idx = blockIdx.x * 256 + threadIdx.x;
  if (idx >= NCLS * DDIM) return;
  float s = 0.f;
  for (int p = 0; p < 512; ++p) s += Pb[(size_t)p * NCLS * DDIM + idx];
  Bout[idx] = s;
}

// ------------------------- C[o] = <B, head_w[o]> + head_b[o] ---------------
__global__ __launch_bounds__(256) void k_head(const float* __restrict__ Bmat,
                                              const float* __restrict__ hw,
                                              const float* __restrict__ hb,
                                              float* __restrict__ Cout) {
  const int o = blockIdx.x, t = threadIdx.x;
  float p = 0.f;
  for (int idx = t; idx < NCLS * DDIM; idx += 256)
    p += Bmat[idx] * hw[(size_t)o * NCLS * DDIM + idx];
#pragma unroll
  for (int m = 1; m < 64; m <<= 1) p += __shfl_xor(p, m, 64);
  __shared__ float w[4];
  if ((t & 63) == 0) w[t >> 6] = p;
  __syncthreads();
  if (t == 0) Cout[o] = w[0] + w[1] + w[2] + w[3] + hb[o];
}

// ---------------------------------------------------------------------------
extern "C" void kernel_launch(void* const* d_in, const int* in_sizes, int n_in,
                              void* d_out, int out_size, void* d_ws, size_t ws_size,
                              hipStream_t stream) {
  const float* features   = (const float*)d_in[0];
  const float* c_in       = (const float*)d_in[1];
  const float* key_w      = (const float*)d_in[2];
  const float* key_b      = (const float*)d_in[3];
  const float* key_g      = (const float*)d_in[4];
  const float* key_beta   = (const float*)d_in[5];
  const float* query_w    = (const float*)d_in[6];
  const float* query_b    = (const float*)d_in[7];
  const float* query_g    = (const float*)d_in[8];
  const float* query_beta = (const float*)d_in[9];
  const float* value_w    = (const float*)d_in[10];
  const float* value_b    = (const float*)d_in[11];
  const float* value_g    = (const float*)d_in[12];
  const float* value_beta = (const float*)d_in[13];
  const float* head_w     = (const float*)d_in[14];
  const float* head_b     = (const float*)d_in[15];

  char* ws = (char*)d_ws;
  const size_t SZB = (size_t)MP * DDIM * 2;             // 102,760,448 B
  u16* Xb   = (u16*)ws;                                 // [MP,1024] features bf16
  u16* HbK  = (u16*)(ws + SZB);                         // [MP,1024] pre-LN K
  u16* HbVQ = Xb;                                       // [MP,2048] aliases Xb|HbK (both dead)
  u16* Kb   = (u16*)(ws + 2 * SZB);                     // [MP,1024]
  u16* Vb   = Kb;                                       // reuse after VQ-GEMM
  size_t off = 3 * SZB;
  u16* Wk  = (u16*)(ws + off); off += (size_t)DDIM * DDIM * 2;
  u16* Wvq = (u16*)(ws + off); off += (size_t)2 * DDIM * DDIM * 2;
  float* logits = (float*)(ws + off); off += ((size_t)NROWS * NCLS * 4 + 255) & ~(size_t)255;
  float* Pb  = (float*)(ws + off); off += (size_t)512 * NCLS * DDIM * 4;
  u16* qm    = (u16*)(ws + off); off += ((size_t)NCLS * DDIM * 2 + 255) & ~(size_t)255;
  float* Pmax = (float*)(ws + off); off += ((size_t)128 * NCLS * 4 + 255) & ~(size_t)255;
  float* Psum = (float*)(ws + off); off += ((size_t)128 * NCLS * 4 + 255) & ~(size_t)255;
  float* argv = (float*)(ws + off); off += ((size_t)128 * NCLS * 4 + 255) & ~(size_t)255;
  int*   argi = (int*)  (ws + off); off += ((size_t)128 * NCLS * 4 + 255) & ~(size_t)255;

  float* Cout = (float*)d_out;                          // [7]
  float* Aout = Cout + NCLS;                            // [50000,7]
  float* Bout = Aout + (size_t)NROWS * NCLS;            // [7,1024]

  // argmax partials + dtype converts
  k_arg1<<<128, 256, 0, stream>>>(c_in, argv, argi);
  k_convw<<<384, 256, 0, stream>>>(key_w, value_w, query_w, Wk, Wvq);
  k_convert<<<2048, 256, 0, stream>>>(features, Xb, MP, NROWS);

  // K chain: 256^2 phased GEMM (196 x 4 tiles), then LN (zero-pads to MP)
  k_gemm256<<<784, 512, 131072, stream>>>(Xb, Wk, HbK, 2, 1024);
  k_ln_k<<<MPD4, 256, 0, stream>>>(HbK, key_b, key_g, key_beta, Kb);

  // merged V|Q GEMM: 256^2 phased kernel (196 x 8 tiles); HbVQ aliases Xb|HbK
  k_gemm256<<<1568, 512, 131072, stream>>>(Kb, Wvq, HbVQ, 3, 2048);
  k_qmax2<<<NCLS, 64, 0, stream>>>(argv, argi, HbVQ, query_b, query_g, query_beta, qm);
  k_ln_vq<<<2 * MPD4, 256, 0, stream>>>(HbVQ, value_b, value_g, value_beta,
                                        query_b, query_g, query_beta, qm, Vb, logits);

  // softmax over axis 0: one-pass partials, rescale-fin in consumer
  k_softpart<<<128, 256, 0, stream>>>(logits, Pmax, Psum);

  // B = A^T V (A materialized on the fly), head contraction
  k_bpart<<<512, 256, 0, stream>>>(logits, Pmax, Psum, Vb, Aout, Pb);
  k_bred<<<28, 256, 0, stream>>>(Pb, Bout);
  k_head<<<NCLS, 256, 0, stream>>>(Bout, head_w, head_b, Cout);
}